// Round 6
// baseline (780.748 us; speedup 1.0000x reference)
//
#include <hip/hip_runtime.h>

// Problem constants (fixed by the reference setup_inputs)
#define V_N   50000
#define B_N   4
#define C_IN  128
#define C_OUT 128
#define E_N   800000
#define F_N   512                 // B_N * C_IN features per vertex
#define M_TOT 200000              // V_N * B_N rows of the (v,b) GEMM view

#define SCAN_BLK  1024                        // elements per scan block (256 thr x 4)
#define SCAN_NB   ((V_N + SCAN_BLK - 1) / SCAN_BLK)   // 49

typedef unsigned short ushort_t;
typedef __attribute__((ext_vector_type(8))) short short8;   // 8 bf16 (4 VGPRs)
typedef __attribute__((ext_vector_type(4))) float f32x4;

__device__ __forceinline__ float bf_lo(unsigned u) { return __uint_as_float(u << 16); }
__device__ __forceinline__ float bf_hi(unsigned u) { return __uint_as_float(u & 0xFFFF0000u); }
__device__ __forceinline__ ushort_t f2bf(float f) {      // RNE
    unsigned u = __float_as_uint(f);
    u += 0x7FFFu + ((u >> 16) & 1u);
    return (ushort_t)(u >> 16);
}

// ---------------------------------------------------------------------------
// 1) Transpose x (B,Cin,V) fp32 -> x0 (V, F) bf16
// ---------------------------------------------------------------------------
__global__ __launch_bounds__(256) void k_transpose_in(const float* __restrict__ x,
                                                      ushort_t* __restrict__ x0) {
    __shared__ float tile[32][33];
    int vb = blockIdx.x * 32;
    int fb = blockIdx.y * 32;
    int tx = threadIdx.x, ty = threadIdx.y;   // 32 x 8
#pragma unroll
    for (int i = 0; i < 32; i += 8) {
        int f = fb + ty + i, v = vb + tx;
        float val = 0.f;
        if (v < V_N) val = x[(size_t)f * V_N + v];
        tile[ty + i][tx] = val;
    }
    __syncthreads();
#pragma unroll
    for (int i = 0; i < 32; i += 8) {
        int v = vb + ty + i, f = fb + tx;
        if (v < V_N) x0[(size_t)v * F_N + f] = f2bf(tile[tx][ty + i]);
    }
}

// ---------------------------------------------------------------------------
// 2) CSR build: histogram -> 3-stage device-wide scan -> scatter
// ---------------------------------------------------------------------------
__global__ __launch_bounds__(256) void k_hist(const int* __restrict__ row,
                                              int* __restrict__ counts) {
    int e = blockIdx.x * blockDim.x + threadIdx.x;
    if (e < E_N) atomicAdd(&counts[row[e]], 1);
}

// Stage 1: block-local exclusive scan of 1024 counts per block (256 thr x 4).
__global__ __launch_bounds__(256) void k_scan_blk(const int* __restrict__ counts,
                                                  int* __restrict__ row_ptr,
                                                  int* __restrict__ blk_sums) {
    __shared__ int s[256];
    int t = threadIdx.x;
    int base = blockIdx.x * SCAN_BLK + t * 4;
    int c0 = (base + 0 < V_N) ? counts[base + 0] : 0;
    int c1 = (base + 1 < V_N) ? counts[base + 1] : 0;
    int c2 = (base + 2 < V_N) ? counts[base + 2] : 0;
    int c3 = (base + 3 < V_N) ? counts[base + 3] : 0;
    int p1 = c0, p2 = c0 + c1, p3 = c0 + c1 + c2, tot = p3 + c3;
    s[t] = tot;
    __syncthreads();
#pragma unroll
    for (int off = 1; off < 256; off <<= 1) {
        int v = (t >= off) ? s[t - off] : 0;
        __syncthreads();
        s[t] += v;
        __syncthreads();
    }
    int excl = (t == 0) ? 0 : s[t - 1];
    if (base + 0 < V_N) row_ptr[base + 0] = excl;
    if (base + 1 < V_N) row_ptr[base + 1] = excl + p1;
    if (base + 2 < V_N) row_ptr[base + 2] = excl + p2;
    if (base + 3 < V_N) row_ptr[base + 3] = excl + p3;
    if (t == 255) blk_sums[blockIdx.x] = s[255];
}

// Stage 2: inclusive scan of the 49 block sums in one wave.
__global__ __launch_bounds__(64) void k_scan_top(const int* __restrict__ blk_sums,
                                                 int* __restrict__ blk_off) {
    int t = threadIdx.x;                      // one wave of 64 lanes
    int v = (t < SCAN_NB) ? blk_sums[t] : 0;
#pragma unroll
    for (int off = 1; off < 64; off <<= 1) {
        int u = __shfl_up(v, off);
        if (t >= off) v += u;
    }
    blk_off[t] = v;                           // inclusive prefix
}

// Stage 3: add block offsets, mirror into next[], write row_ptr[V].
__global__ __launch_bounds__(256) void k_scan_add(const int* __restrict__ blk_off,
                                                  int* __restrict__ row_ptr,
                                                  int* __restrict__ next) {
    int b = blockIdx.x, t = threadIdx.x;
    int off = (b == 0) ? 0 : blk_off[b - 1];
    int base = b * SCAN_BLK + t * 4;
#pragma unroll
    for (int i = 0; i < 4; i++) {
        int idx = base + i;
        if (idx < V_N) {
            int rv = row_ptr[idx] + off;
            row_ptr[idx] = rv;
            next[idx]    = rv;
        }
    }
    if (b == 0 && t == 0) row_ptr[V_N] = blk_off[SCAN_NB - 1];
}

__global__ __launch_bounds__(256) void k_scatter(const int* __restrict__ row,
                                                 const int* __restrict__ col,
                                                 const float* __restrict__ vals,
                                                 int* __restrict__ next,
                                                 int2* __restrict__ edges) {
    int e = blockIdx.x * blockDim.x + threadIdx.x;
    if (e < E_N) {
        int r = row[e];
        int pos = atomicAdd(&next[r], 1);
        edges[pos] = make_int2(col[e], __float_as_int(vals[e]));
    }
}

// ---------------------------------------------------------------------------
// 3) Weight prep: W (4,Cin,Cout) fp32 -> Wt (4,Cout,Cin) bf16  (B^T layout)
// ---------------------------------------------------------------------------
__global__ __launch_bounds__(256) void k_wprep(const float* __restrict__ W,
                                               ushort_t* __restrict__ Wt) {
    int i = blockIdx.x * 256 + threadIdx.x;       // 65536 total
    int k = i >> 14, c = (i >> 7) & 127, o = i & 127;
    Wt[((size_t)k * 128 + o) * 128 + c] = f2bf(W[i]);
}

// ---------------------------------------------------------------------------
// 4) SpMM (bf16, fp32 accumulate) + Chebyshev combine, XCD-pinned quarters.
//    quarter = blockIdx & 3, rowblock = blockIdx >> 2. Since workgroups map
//    to XCDs round-robin (bid % 8), XCD g only ever touches feature-quarter
//    g & 3 -> per-XCD src working set = V*256B = 12.8 MB (vs 51 MB), so the
//    4 MB XCD L2 captures most gather reuse.
//    Wave = (row, quarter): lane owns 2 bf16 (4 B); per edge the wave reads
//    256 B contiguous. 4x edge unroll as in the proven round-1 kernel.
//    dst[r,q] = alpha * sum_e val[e]*src[col[e],q] + beta*prev[r,q]
// ---------------------------------------------------------------------------
__global__ __launch_bounds__(256) void k_spmm_bf16(const int* __restrict__ row_ptr,
                                                   const int2* __restrict__ edges,
                                                   const ushort_t* __restrict__ src,
                                                   const ushort_t* __restrict__ prev,
                                                   ushort_t* __restrict__ dst,
                                                   float alpha, float beta,
                                                   int has_prev) {
    int lane = threadIdx.x & 63;
    int wid  = threadIdx.x >> 6;
    int q    = blockIdx.x & 3;                   // feature quarter (XCD-pinned)
    int r    = (blockIdx.x >> 2) * 4 + wid;      // dst row
    int e0 = row_ptr[r], e1 = row_ptr[r + 1];
    float aL = 0.f, aH = 0.f;
    const ushort_t* sp = src + q * 128 + lane * 2;   // 4 B per lane

    int e = e0;
    for (; e + 4 <= e1; e += 4) {
        int2 E0 = edges[e], E1 = edges[e + 1], E2 = edges[e + 2], E3 = edges[e + 3];
        unsigned g0 = *(const unsigned*)(sp + (size_t)E0.x * F_N);
        unsigned g1 = *(const unsigned*)(sp + (size_t)E1.x * F_N);
        unsigned g2 = *(const unsigned*)(sp + (size_t)E2.x * F_N);
        unsigned g3 = *(const unsigned*)(sp + (size_t)E3.x * F_N);
        float w0 = __int_as_float(E0.y), w1 = __int_as_float(E1.y);
        float w2 = __int_as_float(E2.y), w3 = __int_as_float(E3.y);
        aL += w0 * bf_lo(g0); aH += w0 * bf_hi(g0);
        aL += w1 * bf_lo(g1); aH += w1 * bf_hi(g1);
        aL += w2 * bf_lo(g2); aH += w2 * bf_hi(g2);
        aL += w3 * bf_lo(g3); aH += w3 * bf_hi(g3);
    }
    for (; e < e1; e++) {
        int2 E = edges[e];
        unsigned gv = *(const unsigned*)(sp + (size_t)E.x * F_N);
        float wv = __int_as_float(E.y);
        aL += wv * bf_lo(gv); aH += wv * bf_hi(gv);
    }

    size_t off = (size_t)r * F_N + q * 128 + lane * 2;
    float rl, rh;
    if (has_prev) {
        unsigned pv = *(const unsigned*)(prev + off);
        rl = alpha * aL + beta * bf_lo(pv);
        rh = alpha * aH + beta * bf_hi(pv);
    } else {
        rl = alpha * aL; rh = alpha * aH;
    }
    ushort_t res[2] = {f2bf(rl), f2bf(rh)};
    *(unsigned*)(dst + off) = *(const unsigned*)res;
}

// ---------------------------------------------------------------------------
// 5) MFMA GEMM over all 4 Chebyshev orders, fused bias + output transpose.
// ---------------------------------------------------------------------------
__global__ __launch_bounds__(256, 2) void k_gemm_mfma(
        const ushort_t* __restrict__ X0, const ushort_t* __restrict__ X1,
        const ushort_t* __restrict__ X2, const ushort_t* __restrict__ X3,
        const ushort_t* __restrict__ Wt, const float* __restrict__ bias,
        float* __restrict__ out) {
    __shared__ ushort_t As[128][40];   // stride 80 B: 16B-aligned, uniform banks
    __shared__ ushort_t Bs[128][40];
    __shared__ float    Cs[64][133];   // epilogue transpose staging

    int tid  = threadIdx.x;
    int lane = tid & 63;
    int wave = tid >> 6;
    int wm = wave >> 1, wn = wave & 1;
    int quad = lane >> 4, l15 = lane & 15;
    int m_blk = blockIdx.x * 128;

    f32x4 acc[4][4];
#pragma unroll
    for (int fi = 0; fi < 4; fi++)
#pragma unroll
        for (int fj = 0; fj < 4; fj++) {
            acc[fi][fj][0] = 0.f; acc[fi][fj][1] = 0.f;
            acc[fi][fj][2] = 0.f; acc[fi][fj][3] = 0.f;
        }

    const ushort_t* Xb[4] = {X0, X1, X2, X3};

    for (int kb = 0; kb < 4; kb++) {
        const ushort_t* A = Xb[kb];
        const ushort_t* W = Wt + (size_t)kb * (128 * 128);
        for (int kk = 0; kk < 128; kk += 32) {
            __syncthreads();
#pragma unroll
            for (int i = 0; i < 2; i++) {
                int id = tid + i * 256;
                int rr = id >> 2, p = id & 3;
                int gm = m_blk + rr; if (gm >= M_TOT) gm = M_TOT - 1;
                *(uint4*)&As[rr][p * 8] = *(const uint4*)&A[(size_t)gm * 128 + kk + p * 8];
                *(uint4*)&Bs[rr][p * 8] = *(const uint4*)&W[(size_t)rr * 128 + kk + p * 8];
            }
            __syncthreads();
            short8 a[4], b[4];
#pragma unroll
            for (int f = 0; f < 4; f++) {
                a[f] = *(const short8*)&As[wm * 64 + f * 16 + l15][quad * 8];
                b[f] = *(const short8*)&Bs[wn * 64 + f * 16 + l15][quad * 8];
            }
#pragma unroll
            for (int fi = 0; fi < 4; fi++)
#pragma unroll
                for (int fj = 0; fj < 4; fj++)
                    acc[fi][fj] = __builtin_amdgcn_mfma_f32_16x16x32_bf16(
                        a[fi], b[fj], acc[fi][fj], 0, 0, 0);
        }
    }

    // epilogue: 2 chunks of 64 m-rows -> LDS -> transposed global store
    int v_blk = m_blk >> 2;
    for (int h = 0; h < 2; h++) {
        __syncthreads();
        if (wm == h) {
#pragma unroll
            for (int fi = 0; fi < 4; fi++)
#pragma unroll
                for (int fj = 0; fj < 4; fj++) {
                    int ml = fi * 16 + quad * 4;
                    int n  = wn * 64 + fj * 16 + l15;
#pragma unroll
                    for (int reg = 0; reg < 4; reg++)
                        Cs[ml + reg][n] = acc[fi][fj][reg];
                }
        }
        __syncthreads();
#pragma unroll
        for (int i = 0; i < 8; i++) {
            int idx = tid + i * 256;          // 0..2047
            int v4  = idx & 3;                // float4-chunk of v
            int o   = (idx >> 2) & 127;
            int b   = idx >> 9;               // 0..3
            int vl  = v4 * 4;
            float bv = bias[o];
            float r0 = Cs[(vl + 0) * 4 + b][o] + bv;
            float r1 = Cs[(vl + 1) * 4 + b][o] + bv;
            float r2 = Cs[(vl + 2) * 4 + b][o] + bv;
            float r3 = Cs[(vl + 3) * 4 + b][o] + bv;
            int v0 = v_blk + h * 16 + vl;
            float* op = out + ((size_t)b * C_OUT + o) * V_N + v0;
            if (v0 + 3 < V_N) {
                *(float4*)op = make_float4(r0, r1, r2, r3);
            } else {
                if (v0     < V_N) op[0] = r0;
                if (v0 + 1 < V_N) op[1] = r1;
                if (v0 + 2 < V_N) op[2] = r2;
                if (v0 + 3 < V_N) op[3] = r3;
            }
        }
    }
}

// ---------------------------------------------------------------------------
extern "C" void kernel_launch(void* const* d_in, const int* in_sizes, int n_in,
                              void* d_out, int out_size, void* d_ws, size_t ws_size,
                              hipStream_t stream) {
    const float* x        = (const float*)d_in[0];
    const int*   edge_row = (const int*)  d_in[1];
    const int*   edge_col = (const int*)  d_in[2];
    const float* edge_val = (const float*)d_in[3];
    const float* weights  = (const float*)d_in[4];
    const float* biases   = (const float*)d_in[5];
    float* out = (float*)d_out;

    // workspace layout: x0..x3 (bf16, V*F each) | Wt (bf16) | int arrays | edges
    const size_t XSZ = (size_t)V_N * F_N;         // 25.6M elements
    ushort_t* x0 = (ushort_t*)d_ws;
    ushort_t* x1 = x0 + XSZ;
    ushort_t* x2 = x1 + XSZ;
    ushort_t* x3 = x2 + XSZ;
    ushort_t* Wt = x3 + XSZ;                      // 4*128*128
    int* iw      = (int*)(Wt + 4 * 128 * 128);
    int* row_ptr = iw;                            // V+1
    int* counts  = iw + 50016;
    int* nxt     = iw + 100032;
    int* blk_sums= iw + 150048;                   // 49 used (64 reserved)
    int* blk_off = iw + 150112;                   // 49 used (64 reserved)
    int2* edges  = (int2*)(iw + 150176);          // E packed {col, val}
    // total ws ~ 212 MB

    dim3 tb(32, 8);
    dim3 tgrid((V_N + 31) / 32, F_N / 32);

    // 1) transpose input -> x0 (bf16)
    k_transpose_in<<<tgrid, tb, 0, stream>>>(x, x0);

    // 2) CSR build
    hipMemsetAsync(counts, 0, V_N * sizeof(int), stream);
    k_hist<<<(E_N + 255) / 256, 256, 0, stream>>>(edge_row, counts);
    k_scan_blk<<<SCAN_NB, 256, 0, stream>>>(counts, row_ptr, blk_sums);
    k_scan_top<<<1, 64, 0, stream>>>(blk_sums, blk_off);
    k_scan_add<<<SCAN_NB, 256, 0, stream>>>(blk_off, row_ptr, nxt);
    k_scatter<<<(E_N + 255) / 256, 256, 0, stream>>>(edge_row, edge_col, edge_val,
                                                     nxt, edges);

    // 3) weights -> bf16, transposed to (k, o, c)
    k_wprep<<<256, 256, 0, stream>>>(weights, Wt);

    // 4) Chebyshev recurrence (bf16 state, fp32 accumulate)
    //    grid: (V/4 rowblocks) x (4 quarters), bid = rblk*4 + q so that
    //    bid%8 pins each XCD to a single feature quarter.
    k_spmm_bf16<<<(V_N / 4) * 4, 256, 0, stream>>>(row_ptr, edges, x0, x0, x1,
                                                   1.f, 0.f, 0);
    k_spmm_bf16<<<(V_N / 4) * 4, 256, 0, stream>>>(row_ptr, edges, x1, x0, x2,
                                                   2.f, -1.f, 1);
    k_spmm_bf16<<<(V_N / 4) * 4, 256, 0, stream>>>(row_ptr, edges, x2, x1, x3,
                                                   2.f, -1.f, 1);

    // 5) fused MFMA GEMM (all 4 orders) + bias + transpose to (B,Cout,V)
    k_gemm_mfma<<<(M_TOT + 127) / 128, 256, 0, stream>>>(x0, x1, x2, x3, Wt,
                                                         biases, out);
}

// Round 7
// 698.855 us; speedup vs baseline: 1.1172x; 1.1172x over previous
//
#include <hip/hip_runtime.h>

// Problem constants (fixed by the reference setup_inputs)
#define V_N   50000
#define B_N   4
#define C_IN  128
#define C_OUT 128
#define E_N   800000
#define F_N   512                 // B_N * C_IN features per vertex
#define M_TOT 200000              // V_N * B_N rows of the (v,b) GEMM view

#define SCAN_BLK  1024                        // elements per scan block (256 thr x 4)
#define SCAN_NB   ((V_N + SCAN_BLK - 1) / SCAN_BLK)   // 49

typedef unsigned short ushort_t;
typedef __attribute__((ext_vector_type(8))) short short8;   // 8 bf16 (4 VGPRs)
typedef __attribute__((ext_vector_type(4))) float f32x4;

#define AS1 __attribute__((address_space(1)))
#define AS3 __attribute__((address_space(3)))
// async global->LDS DMA, 16 B per lane. LDS dest: wave-uniform base + lane*16.
__device__ __forceinline__ void gl_lds16(const void* gp, void* lp) {
    __builtin_amdgcn_global_load_lds((const AS1 unsigned int*)gp,
                                     (AS3 unsigned int*)lp, 16, 0, 0);
}

__device__ __forceinline__ float bf_lo(unsigned u) { return __uint_as_float(u << 16); }
__device__ __forceinline__ float bf_hi(unsigned u) { return __uint_as_float(u & 0xFFFF0000u); }
__device__ __forceinline__ ushort_t f2bf(float f) {      // RNE
    unsigned u = __float_as_uint(f);
    u += 0x7FFFu + ((u >> 16) & 1u);
    return (ushort_t)(u >> 16);
}

// ---------------------------------------------------------------------------
// 1) Transpose x (B,Cin,V) fp32 -> x0 (V, F) bf16
// ---------------------------------------------------------------------------
__global__ __launch_bounds__(256) void k_transpose_in(const float* __restrict__ x,
                                                      ushort_t* __restrict__ x0) {
    __shared__ float tile[32][33];
    int vb = blockIdx.x * 32;
    int fb = blockIdx.y * 32;
    int tx = threadIdx.x, ty = threadIdx.y;   // 32 x 8
#pragma unroll
    for (int i = 0; i < 32; i += 8) {
        int f = fb + ty + i, v = vb + tx;
        float val = 0.f;
        if (v < V_N) val = x[(size_t)f * V_N + v];
        tile[ty + i][tx] = val;
    }
    __syncthreads();
#pragma unroll
    for (int i = 0; i < 32; i += 8) {
        int v = vb + ty + i, f = fb + tx;
        if (v < V_N) x0[(size_t)v * F_N + f] = f2bf(tile[tx][ty + i]);
    }
}

// ---------------------------------------------------------------------------
// 2) CSR build: histogram -> 3-stage device-wide scan -> scatter
// ---------------------------------------------------------------------------
__global__ __launch_bounds__(256) void k_hist(const int* __restrict__ row,
                                              int* __restrict__ counts) {
    int e = blockIdx.x * blockDim.x + threadIdx.x;
    if (e < E_N) atomicAdd(&counts[row[e]], 1);
}

__global__ __launch_bounds__(256) void k_scan_blk(const int* __restrict__ counts,
                                                  int* __restrict__ row_ptr,
                                                  int* __restrict__ blk_sums) {
    __shared__ int s[256];
    int t = threadIdx.x;
    int base = blockIdx.x * SCAN_BLK + t * 4;
    int c0 = (base + 0 < V_N) ? counts[base + 0] : 0;
    int c1 = (base + 1 < V_N) ? counts[base + 1] : 0;
    int c2 = (base + 2 < V_N) ? counts[base + 2] : 0;
    int c3 = (base + 3 < V_N) ? counts[base + 3] : 0;
    int p1 = c0, p2 = c0 + c1, p3 = c0 + c1 + c2, tot = p3 + c3;
    s[t] = tot;
    __syncthreads();
#pragma unroll
    for (int off = 1; off < 256; off <<= 1) {
        int v = (t >= off) ? s[t - off] : 0;
        __syncthreads();
        s[t] += v;
        __syncthreads();
    }
    int excl = (t == 0) ? 0 : s[t - 1];
    if (base + 0 < V_N) row_ptr[base + 0] = excl;
    if (base + 1 < V_N) row_ptr[base + 1] = excl + p1;
    if (base + 2 < V_N) row_ptr[base + 2] = excl + p2;
    if (base + 3 < V_N) row_ptr[base + 3] = excl + p3;
    if (t == 255) blk_sums[blockIdx.x] = s[255];
}

__global__ __launch_bounds__(64) void k_scan_top(const int* __restrict__ blk_sums,
                                                 int* __restrict__ blk_off) {
    int t = threadIdx.x;                      // one wave of 64 lanes
    int v = (t < SCAN_NB) ? blk_sums[t] : 0;
#pragma unroll
    for (int off = 1; off < 64; off <<= 1) {
        int u = __shfl_up(v, off);
        if (t >= off) v += u;
    }
    blk_off[t] = v;                           // inclusive prefix
}

__global__ __launch_bounds__(256) void k_scan_add(const int* __restrict__ blk_off,
                                                  int* __restrict__ row_ptr,
                                                  int* __restrict__ next) {
    int b = blockIdx.x, t = threadIdx.x;
    int off = (b == 0) ? 0 : blk_off[b - 1];
    int base = b * SCAN_BLK + t * 4;
#pragma unroll
    for (int i = 0; i < 4; i++) {
        int idx = base + i;
        if (idx < V_N) {
            int rv = row_ptr[idx] + off;
            row_ptr[idx] = rv;
            next[idx]    = rv;
        }
    }
    if (b == 0 && t == 0) row_ptr[V_N] = blk_off[SCAN_NB - 1];
}

__global__ __launch_bounds__(256) void k_scatter(const int* __restrict__ row,
                                                 const int* __restrict__ col,
                                                 const float* __restrict__ vals,
                                                 int* __restrict__ next,
                                                 int2* __restrict__ edges) {
    int e = blockIdx.x * blockDim.x + threadIdx.x;
    if (e < E_N) {
        int r = row[e];
        int pos = atomicAdd(&next[r], 1);
        edges[pos] = make_int2(col[e], __float_as_int(vals[e]));
    }
}

// ---------------------------------------------------------------------------
// 3) Weight prep: W (4,Cin,Cout) fp32 -> Wt (4,Cout,Cin) bf16  (B^T layout)
// ---------------------------------------------------------------------------
__global__ __launch_bounds__(256) void k_wprep(const float* __restrict__ W,
                                               ushort_t* __restrict__ Wt) {
    int i = blockIdx.x * 256 + threadIdx.x;       // 65536 total
    int k = i >> 14, c = (i >> 7) & 127, o = i & 127;
    Wt[((size_t)k * 128 + o) * 128 + c] = f2bf(W[i]);
}

// ---------------------------------------------------------------------------
// 4) SpMM (bf16, fp32 accumulate) + Chebyshev combine.  ROUND-1 EXACT —
//    empirical floor (119.8us) across 4 structural variants (r3/r4/r5/r6).
//    One wave per (row, feature-half): lane owns 4 bf16 (8 B) of a 256-feat
//    half-row. 4x edge unroll -> 4 independent gathers in flight per wave.
// ---------------------------------------------------------------------------
__global__ __launch_bounds__(256) void k_spmm_bf16(const int* __restrict__ row_ptr,
                                                   const int2* __restrict__ edges,
                                                   const ushort_t* __restrict__ src,
                                                   const ushort_t* __restrict__ prev,
                                                   ushort_t* __restrict__ dst,
                                                   float alpha, float beta,
                                                   int has_prev) {
    int lane = threadIdx.x & 63;
    int g = blockIdx.x * 4 + (threadIdx.x >> 6);   // global wave id
    int r = g >> 1;
    int h = g & 1;                                  // feature half
    int e0 = row_ptr[r], e1 = row_ptr[r + 1];
    float a0 = 0.f, a1 = 0.f, a2 = 0.f, a3 = 0.f;
    const ushort_t* sp = src + h * 256 + lane * 4;

    int e = e0;
    for (; e + 4 <= e1; e += 4) {
        int2 E0 = edges[e], E1 = edges[e + 1], E2 = edges[e + 2], E3 = edges[e + 3];
        uint2 g0 = *(const uint2*)(sp + (size_t)E0.x * F_N);
        uint2 g1 = *(const uint2*)(sp + (size_t)E1.x * F_N);
        uint2 g2 = *(const uint2*)(sp + (size_t)E2.x * F_N);
        uint2 g3 = *(const uint2*)(sp + (size_t)E3.x * F_N);
        float w0 = __int_as_float(E0.y), w1 = __int_as_float(E1.y);
        float w2 = __int_as_float(E2.y), w3 = __int_as_float(E3.y);
        a0 += w0 * bf_lo(g0.x); a1 += w0 * bf_hi(g0.x);
        a2 += w0 * bf_lo(g0.y); a3 += w0 * bf_hi(g0.y);
        a0 += w1 * bf_lo(g1.x); a1 += w1 * bf_hi(g1.x);
        a2 += w1 * bf_lo(g1.y); a3 += w1 * bf_hi(g1.y);
        a0 += w2 * bf_lo(g2.x); a1 += w2 * bf_hi(g2.x);
        a2 += w2 * bf_lo(g2.y); a3 += w2 * bf_hi(g2.y);
        a0 += w3 * bf_lo(g3.x); a1 += w3 * bf_hi(g3.x);
        a2 += w3 * bf_lo(g3.y); a3 += w3 * bf_hi(g3.y);
    }
    for (; e < e1; e++) {
        int2 E = edges[e];
        uint2 gv = *(const uint2*)(sp + (size_t)E.x * F_N);
        float w = __int_as_float(E.y);
        a0 += w * bf_lo(gv.x); a1 += w * bf_hi(gv.x);
        a2 += w * bf_lo(gv.y); a3 += w * bf_hi(gv.y);
    }

    size_t off = (size_t)r * F_N + h * 256 + lane * 4;
    if (has_prev) {
        uint2 pv = *(const uint2*)(prev + off);
        a0 = alpha * a0 + beta * bf_lo(pv.x);
        a1 = alpha * a1 + beta * bf_hi(pv.x);
        a2 = alpha * a2 + beta * bf_lo(pv.y);
        a3 = alpha * a3 + beta * bf_hi(pv.y);
    } else {
        a0 *= alpha; a1 *= alpha; a2 *= alpha; a3 *= alpha;
    }
    ushort_t res[4] = {f2bf(a0), f2bf(a1), f2bf(a2), f2bf(a3)};
    *(uint2*)(dst + off) = *(const uint2*)res;
}

// ---------------------------------------------------------------------------
// 5) MFMA GEMM over all 4 Chebyshev orders, fused bias + output transpose.
//    Reworked m97-style: global_load_lds (16B DMA) into LINEAR LDS, BK=64
//    (8 K-steps, half the barriers), XOR chunk-swizzle on BOTH sides
//    (pre-swizzled global source + swizzled ds_read) for conflict-free b128.
// ---------------------------------------------------------------------------
__global__ __launch_bounds__(256, 2) void k_gemm_mfma(
        const ushort_t* __restrict__ X0, const ushort_t* __restrict__ X1,
        const ushort_t* __restrict__ X2, const ushort_t* __restrict__ X3,
        const ushort_t* __restrict__ Wt, const float* __restrict__ bias,
        float* __restrict__ out) {
    __shared__ ushort_t As[128][64];   // linear (DMA dest), 16 KB
    __shared__ ushort_t Bs[128][64];   // linear (DMA dest), 16 KB
    __shared__ float    Cs[64][133];   // epilogue transpose staging, 34 KB

    int tid  = threadIdx.x;
    int lane = tid & 63;
    int wv   = tid >> 6;
    int wm = wv >> 1, wn = wv & 1;
    int quad = lane >> 4, l15 = lane & 15;
    int m_blk = blockIdx.x * 128;

    f32x4 acc[4][4];
#pragma unroll
    for (int fi = 0; fi < 4; fi++)
#pragma unroll
        for (int fj = 0; fj < 4; fj++) {
            acc[fi][fj][0] = 0.f; acc[fi][fj][1] = 0.f;
            acc[fi][fj][2] = 0.f; acc[fi][fj][3] = 0.f;
        }

    const ushort_t* Xb[4] = {X0, X1, X2, X3};

    // staging geometry: one DMA inst = 64 lanes x 16 B = 1 KB = 8 rows of 128 B.
    int rr_s = lane >> 3;              // row within 8-row group
    int pl   = lane & 7;               // 16B chunk slot within row (LDS side)
    for (int kb = 0; kb < 4; kb++) {
        const ushort_t* A = Xb[kb];
        const ushort_t* W = Wt + (size_t)kb * (128 * 128);
        for (int kk = 0; kk < 128; kk += 64) {
            __syncthreads();           // previous step's ds_reads done
#pragma unroll
            for (int i = 0; i < 4; i++) {
                int r0 = (wv * 4 + i) * 8;           // wave-uniform
                int rr = r0 + rr_s;
                int pg = pl ^ (rr & 7);              // pre-swizzled source chunk
                int gm = m_blk + rr; if (gm >= M_TOT) gm = M_TOT - 1;
                gl_lds16(&A[(size_t)gm * 128 + kk + pg * 8], &As[r0][0]);
                gl_lds16(&W[(size_t)rr * 128 + kk + pg * 8], &Bs[r0][0]);
            }
            __syncthreads();           // drains vmcnt -> tiles ready

            short8 a[2][4], b[2][4];
#pragma unroll
            for (int h = 0; h < 2; h++)
#pragma unroll
                for (int f = 0; f < 4; f++) {
                    int ra = wm * 64 + f * 16 + l15;
                    int ca = (h * 4 + quad) ^ (ra & 7);
                    a[h][f] = *(const short8*)&As[ra][ca * 8];
                    int rb = wn * 64 + f * 16 + l15;
                    int cb = (h * 4 + quad) ^ (rb & 7);
                    b[h][f] = *(const short8*)&Bs[rb][cb * 8];
                }
#pragma unroll
            for (int h = 0; h < 2; h++)
#pragma unroll
                for (int fi = 0; fi < 4; fi++)
#pragma unroll
                    for (int fj = 0; fj < 4; fj++)
                        acc[fi][fj] = __builtin_amdgcn_mfma_f32_16x16x32_bf16(
                            a[h][fi], b[h][fj], acc[fi][fj], 0, 0, 0);
        }
    }

    // epilogue: 2 chunks of 64 m-rows -> LDS -> transposed global store
    int v_blk = m_blk >> 2;
    for (int h = 0; h < 2; h++) {
        __syncthreads();
        if (wm == h) {
#pragma unroll
            for (int fi = 0; fi < 4; fi++)
#pragma unroll
                for (int fj = 0; fj < 4; fj++) {
                    int ml = fi * 16 + quad * 4;
                    int n  = wn * 64 + fj * 16 + l15;
#pragma unroll
                    for (int reg = 0; reg < 4; reg++)
                        Cs[ml + reg][n] = acc[fi][fj][reg];
                }
        }
        __syncthreads();
#pragma unroll
        for (int i = 0; i < 8; i++) {
            int idx = tid + i * 256;          // 0..2047
            int v4  = idx & 3;                // float4-chunk of v
            int o   = (idx >> 2) & 127;
            int b   = idx >> 9;               // 0..3
            int vl  = v4 * 4;
            float bv = bias[o];
            float r0 = Cs[(vl + 0) * 4 + b][o] + bv;
            float r1 = Cs[(vl + 1) * 4 + b][o] + bv;
            float r2 = Cs[(vl + 2) * 4 + b][o] + bv;
            float r3 = Cs[(vl + 3) * 4 + b][o] + bv;
            int v0 = v_blk + h * 16 + vl;
            float* op = out + ((size_t)b * C_OUT + o) * V_N + v0;
            if (v0 + 3 < V_N) {
                *(float4*)op = make_float4(r0, r1, r2, r3);
            } else {
                if (v0     < V_N) op[0] = r0;
                if (v0 + 1 < V_N) op[1] = r1;
                if (v0 + 2 < V_N) op[2] = r2;
                if (v0 + 3 < V_N) op[3] = r3;
            }
        }
    }
}

// ---------------------------------------------------------------------------
extern "C" void kernel_launch(void* const* d_in, const int* in_sizes, int n_in,
                              void* d_out, int out_size, void* d_ws, size_t ws_size,
                              hipStream_t stream) {
    const float* x        = (const float*)d_in[0];
    const int*   edge_row = (const int*)  d_in[1];
    const int*   edge_col = (const int*)  d_in[2];
    const float* edge_val = (const float*)d_in[3];
    const float* weights  = (const float*)d_in[4];
    const float* biases   = (const float*)d_in[5];
    float* out = (float*)d_out;

    // workspace layout: x0..x3 (bf16, V*F each) | Wt (bf16) | int arrays | edges
    const size_t XSZ = (size_t)V_N * F_N;         // 25.6M elements
    ushort_t* x0 = (ushort_t*)d_ws;
    ushort_t* x1 = x0 + XSZ;
    ushort_t* x2 = x1 + XSZ;
    ushort_t* x3 = x2 + XSZ;
    ushort_t* Wt = x3 + XSZ;                      // 4*128*128
    int* iw      = (int*)(Wt + 4 * 128 * 128);
    int* row_ptr = iw;                            // V+1
    int* counts  = iw + 50016;
    int* nxt     = iw + 100032;
    int* blk_sums= iw + 150048;                   // 49 used (64 reserved)
    int* blk_off = iw + 150112;                   // 49 used (64 reserved)
    int2* edges  = (int2*)(iw + 150176);          // E packed {col, val}
    // total ws ~ 212 MB

    dim3 tb(32, 8);
    dim3 tgrid((V_N + 31) / 32, F_N / 32);

    // 1) transpose input -> x0 (bf16)
    k_transpose_in<<<tgrid, tb, 0, stream>>>(x, x0);

    // 2) CSR build
    hipMemsetAsync(counts, 0, V_N * sizeof(int), stream);
    k_hist<<<(E_N + 255) / 256, 256, 0, stream>>>(edge_row, counts);
    k_scan_blk<<<SCAN_NB, 256, 0, stream>>>(counts, row_ptr, blk_sums);
    k_scan_top<<<1, 64, 0, stream>>>(blk_sums, blk_off);
    k_scan_add<<<SCAN_NB, 256, 0, stream>>>(blk_off, row_ptr, nxt);
    k_scatter<<<(E_N + 255) / 256, 256, 0, stream>>>(edge_row, edge_col, edge_val,
                                                     nxt, edges);

    // 3) weights -> bf16, transposed to (k, o, c)
    k_wprep<<<256, 256, 0, stream>>>(weights, Wt);

    // 4) Chebyshev recurrence (bf16 state, fp32 accumulate)
    //    grid: V rows x 2 halves, 4 waves per block
    k_spmm_bf16<<<V_N * 2 / 4, 256, 0, stream>>>(row_ptr, edges, x0, x0, x1,
                                                 1.f, 0.f, 0);
    k_spmm_bf16<<<V_N * 2 / 4, 256, 0, stream>>>(row_ptr, edges, x1, x0, x2,
                                                 2.f, -1.f, 1);
    k_spmm_bf16<<<V_N * 2 / 4, 256, 0, stream>>>(row_ptr, edges, x2, x1, x3,
                                                 2.f, -1.f, 1);

    // 5) fused MFMA GEMM (all 4 orders) + bias + transpose to (B,Cout,V)
    k_gemm_mfma<<<(M_TOT + 127) / 128, 256, 0, stream>>>(x0, x1, x2, x3, Wt,
                                                         biases, out);
}

// Round 8
// 687.611 us; speedup vs baseline: 1.1355x; 1.0164x over previous
//
#include <hip/hip_runtime.h>

// Problem constants (fixed by the reference setup_inputs)
#define V_N   50000
#define B_N   4
#define C_IN  128
#define C_OUT 128
#define E_N   800000
#define F_N   512                 // B_N * C_IN features per vertex
#define M_TOT 200000              // V_N * B_N rows of the (v,b) GEMM view

#define SCAN_BLK  1024                        // elements per scan block (256 thr x 4)
#define SCAN_NB   ((V_N + SCAN_BLK - 1) / SCAN_BLK)   // 49

typedef unsigned short ushort_t;
typedef __attribute__((ext_vector_type(8))) short short8;   // 8 bf16 (4 VGPRs)
typedef __attribute__((ext_vector_type(4))) float f32x4;

#define AS1 __attribute__((address_space(1)))
#define AS3 __attribute__((address_space(3)))
// async global->LDS DMA, 16 B per lane. LDS dest: wave-uniform base + lane*16.
__device__ __forceinline__ void gl_lds16(const void* gp, void* lp) {
    __builtin_amdgcn_global_load_lds((const AS1 unsigned int*)gp,
                                     (AS3 unsigned int*)lp, 16, 0, 0);
}

__device__ __forceinline__ float bf_lo(unsigned u) { return __uint_as_float(u << 16); }
__device__ __forceinline__ float bf_hi(unsigned u) { return __uint_as_float(u & 0xFFFF0000u); }
__device__ __forceinline__ ushort_t f2bf(float f) {      // RNE
    unsigned u = __float_as_uint(f);
    u += 0x7FFFu + ((u >> 16) & 1u);
    return (ushort_t)(u >> 16);
}

// ---------------------------------------------------------------------------
// 1) Transpose x (B,Cin,V) fp32 -> x0 (V, F) bf16.  float4 reads (16 B/lane),
//    32f x 128v LDS tile (pad 133 -> distinct banks per f-group), uint2 writes.
// ---------------------------------------------------------------------------
__global__ __launch_bounds__(256) void k_transpose_in(const float* __restrict__ x,
                                                      ushort_t* __restrict__ x0) {
    __shared__ float tile[32][133];   // [f][v]
    int vb = blockIdx.x * 128;
    int fb = blockIdx.y * 32;
    int tid = threadIdx.x;
    int fo = tid >> 5;               // 0..7
    int vo = (tid & 31) * 4;         // 0..124
#pragma unroll
    for (int p = 0; p < 4; p++) {
        int f = fb + fo + p * 8;
        int v = vb + vo;
        float4 val = make_float4(0.f, 0.f, 0.f, 0.f);
        const float* xp = &x[(size_t)f * V_N + v];
        if (v + 3 < V_N) {
            val = *(const float4*)xp;
        } else {
            if (v     < V_N) val.x = xp[0];
            if (v + 1 < V_N) val.y = xp[1];
            if (v + 2 < V_N) val.z = xp[2];
            if (v + 3 < V_N) val.w = xp[3];
        }
        tile[fo + p * 8][vo + 0] = val.x;
        tile[fo + p * 8][vo + 1] = val.y;
        tile[fo + p * 8][vo + 2] = val.z;
        tile[fo + p * 8][vo + 3] = val.w;
    }
    __syncthreads();
    int fl = (tid & 7) * 4;          // 0,4,..,28
    int vbase = tid >> 3;            // 0..31
#pragma unroll
    for (int i = 0; i < 4; i++) {
        int vloc = vbase + i * 32;
        int v = vb + vloc;
        if (v < V_N) {
            ushort_t r[4] = { f2bf(tile[fl + 0][vloc]), f2bf(tile[fl + 1][vloc]),
                              f2bf(tile[fl + 2][vloc]), f2bf(tile[fl + 3][vloc]) };
            *(uint2*)&x0[(size_t)v * F_N + fb + fl] = *(const uint2*)r;
        }
    }
}

// ---------------------------------------------------------------------------
// 2) CSR build: histogram -> 3-stage device-wide scan -> scatter
// ---------------------------------------------------------------------------
__global__ __launch_bounds__(256) void k_hist(const int* __restrict__ row,
                                              int* __restrict__ counts) {
    int e = blockIdx.x * blockDim.x + threadIdx.x;
    if (e < E_N) atomicAdd(&counts[row[e]], 1);
}

__global__ __launch_bounds__(256) void k_scan_blk(const int* __restrict__ counts,
                                                  int* __restrict__ row_ptr,
                                                  int* __restrict__ blk_sums) {
    __shared__ int s[256];
    int t = threadIdx.x;
    int base = blockIdx.x * SCAN_BLK + t * 4;
    int c0 = (base + 0 < V_N) ? counts[base + 0] : 0;
    int c1 = (base + 1 < V_N) ? counts[base + 1] : 0;
    int c2 = (base + 2 < V_N) ? counts[base + 2] : 0;
    int c3 = (base + 3 < V_N) ? counts[base + 3] : 0;
    int p1 = c0, p2 = c0 + c1, p3 = c0 + c1 + c2, tot = p3 + c3;
    s[t] = tot;
    __syncthreads();
#pragma unroll
    for (int off = 1; off < 256; off <<= 1) {
        int v = (t >= off) ? s[t - off] : 0;
        __syncthreads();
        s[t] += v;
        __syncthreads();
    }
    int excl = (t == 0) ? 0 : s[t - 1];
    if (base + 0 < V_N) row_ptr[base + 0] = excl;
    if (base + 1 < V_N) row_ptr[base + 1] = excl + p1;
    if (base + 2 < V_N) row_ptr[base + 2] = excl + p2;
    if (base + 3 < V_N) row_ptr[base + 3] = excl + p3;
    if (t == 255) blk_sums[blockIdx.x] = s[255];
}

__global__ __launch_bounds__(64) void k_scan_top(const int* __restrict__ blk_sums,
                                                 int* __restrict__ blk_off) {
    int t = threadIdx.x;                      // one wave of 64 lanes
    int v = (t < SCAN_NB) ? blk_sums[t] : 0;
#pragma unroll
    for (int off = 1; off < 64; off <<= 1) {
        int u = __shfl_up(v, off);
        if (t >= off) v += u;
    }
    blk_off[t] = v;                           // inclusive prefix
}

__global__ __launch_bounds__(256) void k_scan_add(const int* __restrict__ blk_off,
                                                  int* __restrict__ row_ptr,
                                                  int* __restrict__ next) {
    int b = blockIdx.x, t = threadIdx.x;
    int off = (b == 0) ? 0 : blk_off[b - 1];
    int base = b * SCAN_BLK + t * 4;
#pragma unroll
    for (int i = 0; i < 4; i++) {
        int idx = base + i;
        if (idx < V_N) {
            int rv = row_ptr[idx] + off;
            row_ptr[idx] = rv;
            next[idx]    = rv;
        }
    }
    if (b == 0 && t == 0) row_ptr[V_N] = blk_off[SCAN_NB - 1];
}

__global__ __launch_bounds__(256) void k_scatter(const int* __restrict__ row,
                                                 const int* __restrict__ col,
                                                 const float* __restrict__ vals,
                                                 int* __restrict__ next,
                                                 int2* __restrict__ edges) {
    int e = blockIdx.x * blockDim.x + threadIdx.x;
    if (e < E_N) {
        int r = row[e];
        int pos = atomicAdd(&next[r], 1);
        edges[pos] = make_int2(col[e], __float_as_int(vals[e]));
    }
}

// ---------------------------------------------------------------------------
// 3) Weight prep with Chebyshev folding.
//    States are pure powers z_k = A^k x0. Since T0=I, T1=A, T2=2A^2-I,
//    T3=4A^3-3A:  sum_k T_k(A) x0 W_k = z0(W0-W2) + z1(W1-3W3) + z2(2W2)
//    + z3(4W3). Fold into Wt (k,o,c) bf16.
// ---------------------------------------------------------------------------
__global__ __launch_bounds__(256) void k_wprep(const float* __restrict__ W,
                                               ushort_t* __restrict__ Wt) {
    int i = blockIdx.x * 256 + threadIdx.x;       // 16384 total: (c,o)
    int c = i >> 7, o = i & 127;
    float w0 = W[0 * 16384 + c * 128 + o];
    float w1 = W[1 * 16384 + c * 128 + o];
    float w2 = W[2 * 16384 + c * 128 + o];
    float w3 = W[3 * 16384 + c * 128 + o];
    Wt[((size_t)0 * 128 + o) * 128 + c] = f2bf(w0 - w2);
    Wt[((size_t)1 * 128 + o) * 128 + c] = f2bf(w1 - 3.f * w3);
    Wt[((size_t)2 * 128 + o) * 128 + c] = f2bf(2.f * w2);
    Wt[((size_t)3 * 128 + o) * 128 + c] = f2bf(4.f * w3);
}

// ---------------------------------------------------------------------------
// 4) Pure-power SpMM (bf16, fp32 accumulate): dst = A * src.  Round-1
//    structure (empirical floor across r3-r6 variants), prev/alpha/beta
//    removed (folded into GEMM weights).
// ---------------------------------------------------------------------------
__global__ __launch_bounds__(256) void k_spmm_bf16(const int* __restrict__ row_ptr,
                                                   const int2* __restrict__ edges,
                                                   const ushort_t* __restrict__ src,
                                                   ushort_t* __restrict__ dst) {
    int lane = threadIdx.x & 63;
    int g = blockIdx.x * 4 + (threadIdx.x >> 6);   // global wave id
    int r = g >> 1;
    int h = g & 1;                                  // feature half
    int e0 = row_ptr[r], e1 = row_ptr[r + 1];
    float a0 = 0.f, a1 = 0.f, a2 = 0.f, a3 = 0.f;
    const ushort_t* sp = src + h * 256 + lane * 4;

    int e = e0;
    for (; e + 4 <= e1; e += 4) {
        int2 E0 = edges[e], E1 = edges[e + 1], E2 = edges[e + 2], E3 = edges[e + 3];
        uint2 g0 = *(const uint2*)(sp + (size_t)E0.x * F_N);
        uint2 g1 = *(const uint2*)(sp + (size_t)E1.x * F_N);
        uint2 g2 = *(const uint2*)(sp + (size_t)E2.x * F_N);
        uint2 g3 = *(const uint2*)(sp + (size_t)E3.x * F_N);
        float w0 = __int_as_float(E0.y), w1 = __int_as_float(E1.y);
        float w2 = __int_as_float(E2.y), w3 = __int_as_float(E3.y);
        a0 += w0 * bf_lo(g0.x); a1 += w0 * bf_hi(g0.x);
        a2 += w0 * bf_lo(g0.y); a3 += w0 * bf_hi(g0.y);
        a0 += w1 * bf_lo(g1.x); a1 += w1 * bf_hi(g1.x);
        a2 += w1 * bf_lo(g1.y); a3 += w1 * bf_hi(g1.y);
        a0 += w2 * bf_lo(g2.x); a1 += w2 * bf_hi(g2.x);
        a2 += w2 * bf_lo(g2.y); a3 += w2 * bf_hi(g2.y);
        a0 += w3 * bf_lo(g3.x); a1 += w3 * bf_hi(g3.x);
        a2 += w3 * bf_lo(g3.y); a3 += w3 * bf_hi(g3.y);
    }
    for (; e < e1; e++) {
        int2 E = edges[e];
        uint2 gv = *(const uint2*)(sp + (size_t)E.x * F_N);
        float w = __int_as_float(E.y);
        a0 += w * bf_lo(gv.x); a1 += w * bf_hi(gv.x);
        a2 += w * bf_lo(gv.y); a3 += w * bf_hi(gv.y);
    }

    size_t off = (size_t)r * F_N + h * 256 + lane * 4;
    ushort_t res[4] = {f2bf(a0), f2bf(a1), f2bf(a2), f2bf(a3)};
    *(uint2*)(dst + off) = *(const uint2*)res;
}

// ---------------------------------------------------------------------------
// 5) MFMA GEMM over the 4 power-states with folded weights, fused bias +
//    output transpose.  m97-style: global_load_lds 16B DMA, BK=64, XOR
//    chunk-swizzle both-sides.
// ---------------------------------------------------------------------------
__global__ __launch_bounds__(256, 2) void k_gemm_mfma(
        const ushort_t* __restrict__ X0, const ushort_t* __restrict__ X1,
        const ushort_t* __restrict__ X2, const ushort_t* __restrict__ X3,
        const ushort_t* __restrict__ Wt, const float* __restrict__ bias,
        float* __restrict__ out) {
    __shared__ ushort_t As[128][64];   // linear (DMA dest), 16 KB
    __shared__ ushort_t Bs[128][64];   // linear (DMA dest), 16 KB
    __shared__ float    Cs[64][133];   // epilogue transpose staging, 34 KB

    int tid  = threadIdx.x;
    int lane = tid & 63;
    int wv   = tid >> 6;
    int wm = wv >> 1, wn = wv & 1;
    int quad = lane >> 4, l15 = lane & 15;
    int m_blk = blockIdx.x * 128;

    f32x4 acc[4][4];
#pragma unroll
    for (int fi = 0; fi < 4; fi++)
#pragma unroll
        for (int fj = 0; fj < 4; fj++) {
            acc[fi][fj][0] = 0.f; acc[fi][fj][1] = 0.f;
            acc[fi][fj][2] = 0.f; acc[fi][fj][3] = 0.f;
        }

    const ushort_t* Xb[4] = {X0, X1, X2, X3};

    // staging geometry: one DMA inst = 64 lanes x 16 B = 1 KB = 8 rows of 128 B.
    int rr_s = lane >> 3;              // row within 8-row group
    int pl   = lane & 7;               // 16B chunk slot within row (LDS side)
    for (int kb = 0; kb < 4; kb++) {
        const ushort_t* A = Xb[kb];
        const ushort_t* W = Wt + (size_t)kb * (128 * 128);
        for (int kk = 0; kk < 128; kk += 64) {
            __syncthreads();           // previous step's ds_reads done
#pragma unroll
            for (int i = 0; i < 4; i++) {
                int r0 = (wv * 4 + i) * 8;           // wave-uniform
                int rr = r0 + rr_s;
                int pg = pl ^ (rr & 7);              // pre-swizzled source chunk
                int gm = m_blk + rr; if (gm >= M_TOT) gm = M_TOT - 1;
                gl_lds16(&A[(size_t)gm * 128 + kk + pg * 8], &As[r0][0]);
                gl_lds16(&W[(size_t)rr * 128 + kk + pg * 8], &Bs[r0][0]);
            }
            __syncthreads();           // drains vmcnt -> tiles ready

            short8 a[2][4], b[2][4];
#pragma unroll
            for (int h = 0; h < 2; h++)
#pragma unroll
                for (int f = 0; f < 4; f++) {
                    int ra = wm * 64 + f * 16 + l15;
                    int ca = (h * 4 + quad) ^ (ra & 7);
                    a[h][f] = *(const short8*)&As[ra][ca * 8];
                    int rb = wn * 64 + f * 16 + l15;
                    int cb = (h * 4 + quad) ^ (rb & 7);
                    b[h][f] = *(const short8*)&Bs[rb][cb * 8];
                }
#pragma unroll
            for (int h = 0; h < 2; h++)
#pragma unroll
                for (int fi = 0; fi < 4; fi++)
#pragma unroll
                    for (int fj = 0; fj < 4; fj++)
                        acc[fi][fj] = __builtin_amdgcn_mfma_f32_16x16x32_bf16(
                            a[h][fi], b[h][fj], acc[fi][fj], 0, 0, 0);
        }
    }

    // epilogue: 2 chunks of 64 m-rows -> LDS -> transposed global store
    int v_blk = m_blk >> 2;
    for (int h = 0; h < 2; h++) {
        __syncthreads();
        if (wm == h) {
#pragma unroll
            for (int fi = 0; fi < 4; fi++)
#pragma unroll
                for (int fj = 0; fj < 4; fj++) {
                    int ml = fi * 16 + quad * 4;
                    int n  = wn * 64 + fj * 16 + l15;
#pragma unroll
                    for (int reg = 0; reg < 4; reg++)
                        Cs[ml + reg][n] = acc[fi][fj][reg];
                }
        }
        __syncthreads();
#pragma unroll
        for (int i = 0; i < 8; i++) {
            int idx = tid + i * 256;          // 0..2047
            int v4  = idx & 3;                // float4-chunk of v
            int o   = (idx >> 2) & 127;
            int b   = idx >> 9;               // 0..3
            int vl  = v4 * 4;
            float bv = bias[o];
            float r0 = Cs[(vl + 0) * 4 + b][o] + bv;
            float r1 = Cs[(vl + 1) * 4 + b][o] + bv;
            float r2 = Cs[(vl + 2) * 4 + b][o] + bv;
            float r3 = Cs[(vl + 3) * 4 + b][o] + bv;
            int v0 = v_blk + h * 16 + vl;
            float* op = out + ((size_t)b * C_OUT + o) * V_N + v0;
            if (v0 + 3 < V_N) {
                *(float4*)op = make_float4(r0, r1, r2, r3);
            } else {
                if (v0     < V_N) op[0] = r0;
                if (v0 + 1 < V_N) op[1] = r1;
                if (v0 + 2 < V_N) op[2] = r2;
                if (v0 + 3 < V_N) op[3] = r3;
            }
        }
    }
}

// ---------------------------------------------------------------------------
extern "C" void kernel_launch(void* const* d_in, const int* in_sizes, int n_in,
                              void* d_out, int out_size, void* d_ws, size_t ws_size,
                              hipStream_t stream) {
    const float* x        = (const float*)d_in[0];
    const int*   edge_row = (const int*)  d_in[1];
    const int*   edge_col = (const int*)  d_in[2];
    const float* edge_val = (const float*)d_in[3];
    const float* weights  = (const float*)d_in[4];
    const float* biases   = (const float*)d_in[5];
    float* out = (float*)d_out;

    // workspace layout: x0..x3 (bf16, V*F each) | Wt (bf16) | int arrays | edges
    const size_t XSZ = (size_t)V_N * F_N;         // 25.6M elements
    ushort_t* x0 = (ushort_t*)d_ws;
    ushort_t* x1 = x0 + XSZ;
    ushort_t* x2 = x1 + XSZ;
    ushort_t* x3 = x2 + XSZ;
    ushort_t* Wt = x3 + XSZ;                      // 4*128*128
    int* iw      = (int*)(Wt + 4 * 128 * 128);
    int* row_ptr = iw;                            // V+1
    int* counts  = iw + 50016;
    int* nxt     = iw + 100032;
    int* blk_sums= iw + 150048;                   // 49 used (64 reserved)
    int* blk_off = iw + 150112;                   // 49 used (64 reserved)
    int2* edges  = (int2*)(iw + 150176);          // E packed {col, val}
    // total ws ~ 212 MB

    // 1) transpose input -> x0 (bf16)
    dim3 tgrid((V_N + 127) / 128, F_N / 32);
    k_transpose_in<<<tgrid, 256, 0, stream>>>(x, x0);

    // 2) CSR build
    hipMemsetAsync(counts, 0, V_N * sizeof(int), stream);
    k_hist<<<(E_N + 255) / 256, 256, 0, stream>>>(edge_row, counts);
    k_scan_blk<<<SCAN_NB, 256, 0, stream>>>(counts, row_ptr, blk_sums);
    k_scan_top<<<1, 64, 0, stream>>>(blk_sums, blk_off);
    k_scan_add<<<SCAN_NB, 256, 0, stream>>>(blk_off, row_ptr, nxt);
    k_scatter<<<(E_N + 255) / 256, 256, 0, stream>>>(edge_row, edge_col, edge_val,
                                                     nxt, edges);

    // 3) weights -> bf16, Chebyshev-folded, transposed to (k, o, c)
    k_wprep<<<64, 256, 0, stream>>>(weights, Wt);

    // 4) Pure power chain z_k = A z_{k-1} (bf16 state, fp32 accumulate)
    k_spmm_bf16<<<V_N * 2 / 4, 256, 0, stream>>>(row_ptr, edges, x0, x1);
    k_spmm_bf16<<<V_N * 2 / 4, 256, 0, stream>>>(row_ptr, edges, x1, x2);
    k_spmm_bf16<<<V_N * 2 / 4, 256, 0, stream>>>(row_ptr, edges, x2, x3);

    // 5) fused MFMA GEMM (folded weights) + bias + transpose to (B,Cout,V)
    k_gemm_mfma<<<(M_TOT + 127) / 128, 256, 0, stream>>>(x0, x1, x2, x3, Wt,
                                                         biases, out);
}

// Round 9
// 686.386 us; speedup vs baseline: 1.1375x; 1.0018x over previous
//
#include <hip/hip_runtime.h>

// Problem constants (fixed by the reference setup_inputs)
#define V_N   50000
#define B_N   4
#define C_IN  128
#define C_OUT 128
#define E_N   800000
#define F_N   512                 // B_N * C_IN features per vertex
#define M_TOT 200000              // V_N * B_N rows of the (v,b) GEMM view

#define SCAN_BLK  1024                        // elements per scan block (256 thr x 4)
#define SCAN_NB   ((V_N + SCAN_BLK - 1) / SCAN_BLK)   // 49

typedef unsigned short ushort_t;
typedef __attribute__((ext_vector_type(8))) short short8;   // 8 bf16 (4 VGPRs)
typedef __attribute__((ext_vector_type(4))) float f32x4;

#define AS1 __attribute__((address_space(1)))
#define AS3 __attribute__((address_space(3)))
// async global->LDS DMA, 16 B per lane. LDS dest: wave-uniform base + lane*16.
__device__ __forceinline__ void gl_lds16(const void* gp, void* lp) {
    __builtin_amdgcn_global_load_lds((const AS1 unsigned int*)gp,
                                     (AS3 unsigned int*)lp, 16, 0, 0);
}

__device__ __forceinline__ float bf_lo(unsigned u) { return __uint_as_float(u << 16); }
__device__ __forceinline__ float bf_hi(unsigned u) { return __uint_as_float(u & 0xFFFF0000u); }
__device__ __forceinline__ ushort_t f2bf(float f) {      // RNE
    unsigned u = __float_as_uint(f);
    u += 0x7FFFu + ((u >> 16) & 1u);
    return (ushort_t)(u >> 16);
}

// ---------------------------------------------------------------------------
// 1) Transpose x (B,Cin,V) fp32 -> x0 (V, F) bf16.  float4 reads (16 B/lane),
//    32f x 128v LDS tile (pad 133 -> distinct banks per f-group), uint2 writes.
// ---------------------------------------------------------------------------
__global__ __launch_bounds__(256) void k_transpose_in(const float* __restrict__ x,
                                                      ushort_t* __restrict__ x0) {
    __shared__ float tile[32][133];   // [f][v]
    int vb = blockIdx.x * 128;
    int fb = blockIdx.y * 32;
    int tid = threadIdx.x;
    int fo = tid >> 5;               // 0..7
    int vo = (tid & 31) * 4;         // 0..124
#pragma unroll
    for (int p = 0; p < 4; p++) {
        int f = fb + fo + p * 8;
        int v = vb + vo;
        float4 val = make_float4(0.f, 0.f, 0.f, 0.f);
        const float* xp = &x[(size_t)f * V_N + v];
        if (v + 3 < V_N) {
            val = *(const float4*)xp;
        } else {
            if (v     < V_N) val.x = xp[0];
            if (v + 1 < V_N) val.y = xp[1];
            if (v + 2 < V_N) val.z = xp[2];
            if (v + 3 < V_N) val.w = xp[3];
        }
        tile[fo + p * 8][vo + 0] = val.x;
        tile[fo + p * 8][vo + 1] = val.y;
        tile[fo + p * 8][vo + 2] = val.z;
        tile[fo + p * 8][vo + 3] = val.w;
    }
    __syncthreads();
    int fl = (tid & 7) * 4;          // 0,4,..,28
    int vbase = tid >> 3;            // 0..31
#pragma unroll
    for (int i = 0; i < 4; i++) {
        int vloc = vbase + i * 32;
        int v = vb + vloc;
        if (v < V_N) {
            ushort_t r[4] = { f2bf(tile[fl + 0][vloc]), f2bf(tile[fl + 1][vloc]),
                              f2bf(tile[fl + 2][vloc]), f2bf(tile[fl + 3][vloc]) };
            *(uint2*)&x0[(size_t)v * F_N + fb + fl] = *(const uint2*)r;
        }
    }
}

// ---------------------------------------------------------------------------
// 2) CSR build: histogram -> 3-stage device-wide scan -> scatter
// ---------------------------------------------------------------------------
__global__ __launch_bounds__(256) void k_hist(const int* __restrict__ row,
                                              int* __restrict__ counts) {
    int e = blockIdx.x * blockDim.x + threadIdx.x;
    if (e < E_N) atomicAdd(&counts[row[e]], 1);
}

__global__ __launch_bounds__(256) void k_scan_blk(const int* __restrict__ counts,
                                                  int* __restrict__ row_ptr,
                                                  int* __restrict__ blk_sums) {
    __shared__ int s[256];
    int t = threadIdx.x;
    int base = blockIdx.x * SCAN_BLK + t * 4;
    int c0 = (base + 0 < V_N) ? counts[base + 0] : 0;
    int c1 = (base + 1 < V_N) ? counts[base + 1] : 0;
    int c2 = (base + 2 < V_N) ? counts[base + 2] : 0;
    int c3 = (base + 3 < V_N) ? counts[base + 3] : 0;
    int p1 = c0, p2 = c0 + c1, p3 = c0 + c1 + c2, tot = p3 + c3;
    s[t] = tot;
    __syncthreads();
#pragma unroll
    for (int off = 1; off < 256; off <<= 1) {
        int v = (t >= off) ? s[t - off] : 0;
        __syncthreads();
        s[t] += v;
        __syncthreads();
    }
    int excl = (t == 0) ? 0 : s[t - 1];
    if (base + 0 < V_N) row_ptr[base + 0] = excl;
    if (base + 1 < V_N) row_ptr[base + 1] = excl + p1;
    if (base + 2 < V_N) row_ptr[base + 2] = excl + p2;
    if (base + 3 < V_N) row_ptr[base + 3] = excl + p3;
    if (t == 255) blk_sums[blockIdx.x] = s[255];
}

__global__ __launch_bounds__(64) void k_scan_top(const int* __restrict__ blk_sums,
                                                 int* __restrict__ blk_off) {
    int t = threadIdx.x;                      // one wave of 64 lanes
    int v = (t < SCAN_NB) ? blk_sums[t] : 0;
#pragma unroll
    for (int off = 1; off < 64; off <<= 1) {
        int u = __shfl_up(v, off);
        if (t >= off) v += u;
    }
    blk_off[t] = v;                           // inclusive prefix
}

__global__ __launch_bounds__(256) void k_scan_add(const int* __restrict__ blk_off,
                                                  int* __restrict__ row_ptr,
                                                  int* __restrict__ next) {
    int b = blockIdx.x, t = threadIdx.x;
    int off = (b == 0) ? 0 : blk_off[b - 1];
    int base = b * SCAN_BLK + t * 4;
#pragma unroll
    for (int i = 0; i < 4; i++) {
        int idx = base + i;
        if (idx < V_N) {
            int rv = row_ptr[idx] + off;
            row_ptr[idx] = rv;
            next[idx]    = rv;
        }
    }
    if (b == 0 && t == 0) row_ptr[V_N] = blk_off[SCAN_NB - 1];
}

__global__ __launch_bounds__(256) void k_scatter(const int* __restrict__ row,
                                                 const int* __restrict__ col,
                                                 const float* __restrict__ vals,
                                                 int* __restrict__ next,
                                                 int2* __restrict__ edges) {
    int e = blockIdx.x * blockDim.x + threadIdx.x;
    if (e < E_N) {
        int r = row[e];
        int pos = atomicAdd(&next[r], 1);
        edges[pos] = make_int2(col[e], __float_as_int(vals[e]));
    }
}

// ---------------------------------------------------------------------------
// 3) Weight prep with Chebyshev folding.
//    States are pure powers z_k = A^k x0. Since T0=I, T1=A, T2=2A^2-I,
//    T3=4A^3-3A:  sum_k T_k(A) x0 W_k = z0(W0-W2) + z1(W1-3W3) + z2(2W2)
//    + z3(4W3). Fold into Wt (k,o,c) bf16.
// ---------------------------------------------------------------------------
__global__ __launch_bounds__(256) void k_wprep(const float* __restrict__ W,
                                               ushort_t* __restrict__ Wt) {
    int i = blockIdx.x * 256 + threadIdx.x;       // 16384 total: (c,o)
    int c = i >> 7, o = i & 127;
    float w0 = W[0 * 16384 + c * 128 + o];
    float w1 = W[1 * 16384 + c * 128 + o];
    float w2 = W[2 * 16384 + c * 128 + o];
    float w3 = W[3 * 16384 + c * 128 + o];
    Wt[((size_t)0 * 128 + o) * 128 + c] = f2bf(w0 - w2);
    Wt[((size_t)1 * 128 + o) * 128 + c] = f2bf(w1 - 3.f * w3);
    Wt[((size_t)2 * 128 + o) * 128 + c] = f2bf(2.f * w2);
    Wt[((size_t)3 * 128 + o) * 128 + c] = f2bf(4.f * w3);
}

// ---------------------------------------------------------------------------
// 4) Pure-power SpMM (bf16, fp32 accumulate): dst = A * src.
//    Round-1 inner loop (empirical floor). NEW: feature-half in the block
//    LSB -> round-robin block->XCD dispatch pins each XCD to one 25.6 MB
//    feature half (even XCDs h=0, odd h=1), halving the per-XCD L2 working
//    set at zero instruction cost. dst stored non-temporal (not re-read
//    in-kernel; keeps L2 for the gather src).
// ---------------------------------------------------------------------------
__global__ __launch_bounds__(256) void k_spmm_bf16(const int* __restrict__ row_ptr,
                                                   const int2* __restrict__ edges,
                                                   const ushort_t* __restrict__ src,
                                                   ushort_t* __restrict__ dst) {
    int lane = threadIdx.x & 63;
    int h = blockIdx.x & 1;                        // feature half (XCD-pinned)
    int r = (blockIdx.x >> 1) * 4 + (threadIdx.x >> 6);
    int e0 = row_ptr[r], e1 = row_ptr[r + 1];
    float a0 = 0.f, a1 = 0.f, a2 = 0.f, a3 = 0.f;
    const ushort_t* sp = src + h * 256 + lane * 4;

    int e = e0;
    for (; e + 4 <= e1; e += 4) {
        int2 E0 = edges[e], E1 = edges[e + 1], E2 = edges[e + 2], E3 = edges[e + 3];
        uint2 g0 = *(const uint2*)(sp + (size_t)E0.x * F_N);
        uint2 g1 = *(const uint2*)(sp + (size_t)E1.x * F_N);
        uint2 g2 = *(const uint2*)(sp + (size_t)E2.x * F_N);
        uint2 g3 = *(const uint2*)(sp + (size_t)E3.x * F_N);
        float w0 = __int_as_float(E0.y), w1 = __int_as_float(E1.y);
        float w2 = __int_as_float(E2.y), w3 = __int_as_float(E3.y);
        a0 += w0 * bf_lo(g0.x); a1 += w0 * bf_hi(g0.x);
        a2 += w0 * bf_lo(g0.y); a3 += w0 * bf_hi(g0.y);
        a0 += w1 * bf_lo(g1.x); a1 += w1 * bf_hi(g1.x);
        a2 += w1 * bf_lo(g1.y); a3 += w1 * bf_hi(g1.y);
        a0 += w2 * bf_lo(g2.x); a1 += w2 * bf_hi(g2.x);
        a2 += w2 * bf_lo(g2.y); a3 += w2 * bf_hi(g2.y);
        a0 += w3 * bf_lo(g3.x); a1 += w3 * bf_hi(g3.x);
        a2 += w3 * bf_lo(g3.y); a3 += w3 * bf_hi(g3.y);
    }
    for (; e < e1; e++) {
        int2 E = edges[e];
        uint2 gv = *(const uint2*)(sp + (size_t)E.x * F_N);
        float w = __int_as_float(E.y);
        a0 += w * bf_lo(gv.x); a1 += w * bf_hi(gv.x);
        a2 += w * bf_lo(gv.y); a3 += w * bf_hi(gv.y);
    }

    size_t off = (size_t)r * F_N + h * 256 + lane * 4;
    ushort_t res[4] = {f2bf(a0), f2bf(a1), f2bf(a2), f2bf(a3)};
    __builtin_nontemporal_store(*(const unsigned long long*)res,
                                (unsigned long long*)(dst + off));
}

// ---------------------------------------------------------------------------
// 5) MFMA GEMM over the 4 power-states with folded weights, fused bias +
//    output transpose.  m97-style: global_load_lds 16B DMA, BK=64, XOR
//    chunk-swizzle both-sides.
// ---------------------------------------------------------------------------
__global__ __launch_bounds__(256, 2) void k_gemm_mfma(
        const ushort_t* __restrict__ X0, const ushort_t* __restrict__ X1,
        const ushort_t* __restrict__ X2, const ushort_t* __restrict__ X3,
        const ushort_t* __restrict__ Wt, const float* __restrict__ bias,
        float* __restrict__ out) {
    __shared__ ushort_t As[128][64];   // linear (DMA dest), 16 KB
    __shared__ ushort_t Bs[128][64];   // linear (DMA dest), 16 KB
    __shared__ float    Cs[64][133];   // epilogue transpose staging, 34 KB

    int tid  = threadIdx.x;
    int lane = tid & 63;
    int wv   = tid >> 6;
    int wm = wv >> 1, wn = wv & 1;
    int quad = lane >> 4, l15 = lane & 15;
    int m_blk = blockIdx.x * 128;

    f32x4 acc[4][4];
#pragma unroll
    for (int fi = 0; fi < 4; fi++)
#pragma unroll
        for (int fj = 0; fj < 4; fj++) {
            acc[fi][fj][0] = 0.f; acc[fi][fj][1] = 0.f;
            acc[fi][fj][2] = 0.f; acc[fi][fj][3] = 0.f;
        }

    const ushort_t* Xb[4] = {X0, X1, X2, X3};

    // staging geometry: one DMA inst = 64 lanes x 16 B = 1 KB = 8 rows of 128 B.
    int rr_s = lane >> 3;              // row within 8-row group
    int pl   = lane & 7;               // 16B chunk slot within row (LDS side)
    for (int kb = 0; kb < 4; kb++) {
        const ushort_t* A = Xb[kb];
        const ushort_t* W = Wt + (size_t)kb * (128 * 128);
        for (int kk = 0; kk < 128; kk += 64) {
            __syncthreads();           // previous step's ds_reads done
#pragma unroll
            for (int i = 0; i < 4; i++) {
                int r0 = (wv * 4 + i) * 8;           // wave-uniform
                int rr = r0 + rr_s;
                int pg = pl ^ (rr & 7);              // pre-swizzled source chunk
                int gm = m_blk + rr; if (gm >= M_TOT) gm = M_TOT - 1;
                gl_lds16(&A[(size_t)gm * 128 + kk + pg * 8], &As[r0][0]);
                gl_lds16(&W[(size_t)rr * 128 + kk + pg * 8], &Bs[r0][0]);
            }
            __syncthreads();           // drains vmcnt -> tiles ready

            short8 a[2][4], b[2][4];
#pragma unroll
            for (int h = 0; h < 2; h++)
#pragma unroll
                for (int f = 0; f < 4; f++) {
                    int ra = wm * 64 + f * 16 + l15;
                    int ca = (h * 4 + quad) ^ (ra & 7);
                    a[h][f] = *(const short8*)&As[ra][ca * 8];
                    int rb = wn * 64 + f * 16 + l15;
                    int cb = (h * 4 + quad) ^ (rb & 7);
                    b[h][f] = *(const short8*)&Bs[rb][cb * 8];
                }
#pragma unroll
            for (int h = 0; h < 2; h++)
#pragma unroll
                for (int fi = 0; fi < 4; fi++)
#pragma unroll
                    for (int fj = 0; fj < 4; fj++)
                        acc[fi][fj] = __builtin_amdgcn_mfma_f32_16x16x32_bf16(
                            a[h][fi], b[h][fj], acc[fi][fj], 0, 0, 0);
        }
    }

    // epilogue: 2 chunks of 64 m-rows -> LDS -> transposed global store
    int v_blk = m_blk >> 2;
    for (int h = 0; h < 2; h++) {
        __syncthreads();
        if (wm == h) {
#pragma unroll
            for (int fi = 0; fi < 4; fi++)
#pragma unroll
                for (int fj = 0; fj < 4; fj++) {
                    int ml = fi * 16 + quad * 4;
                    int n  = wn * 64 + fj * 16 + l15;
#pragma unroll
                    for (int reg = 0; reg < 4; reg++)
                        Cs[ml + reg][n] = acc[fi][fj][reg];
                }
        }
        __syncthreads();
#pragma unroll
        for (int i = 0; i < 8; i++) {
            int idx = tid + i * 256;          // 0..2047
            int v4  = idx & 3;                // float4-chunk of v
            int o   = (idx >> 2) & 127;
            int b   = idx >> 9;               // 0..3
            int vl  = v4 * 4;
            float bv = bias[o];
            float r0 = Cs[(vl + 0) * 4 + b][o] + bv;
            float r1 = Cs[(vl + 1) * 4 + b][o] + bv;
            float r2 = Cs[(vl + 2) * 4 + b][o] + bv;
            float r3 = Cs[(vl + 3) * 4 + b][o] + bv;
            int v0 = v_blk + h * 16 + vl;
            float* op = out + ((size_t)b * C_OUT + o) * V_N + v0;
            if (v0 + 3 < V_N) {
                *(float4*)op = make_float4(r0, r1, r2, r3);
            } else {
                if (v0     < V_N) op[0] = r0;
                if (v0 + 1 < V_N) op[1] = r1;
                if (v0 + 2 < V_N) op[2] = r2;
                if (v0 + 3 < V_N) op[3] = r3;
            }
        }
    }
}

// ---------------------------------------------------------------------------
extern "C" void kernel_launch(void* const* d_in, const int* in_sizes, int n_in,
                              void* d_out, int out_size, void* d_ws, size_t ws_size,
                              hipStream_t stream) {
    const float* x        = (const float*)d_in[0];
    const int*   edge_row = (const int*)  d_in[1];
    const int*   edge_col = (const int*)  d_in[2];
    const float* edge_val = (const float*)d_in[3];
    const float* weights  = (const float*)d_in[4];
    const float* biases   = (const float*)d_in[5];
    float* out = (float*)d_out;

    // workspace layout: x0..x3 (bf16, V*F each) | Wt (bf16) | int arrays | edges
    const size_t XSZ = (size_t)V_N * F_N;         // 25.6M elements
    ushort_t* x0 = (ushort_t*)d_ws;
    ushort_t* x1 = x0 + XSZ;
    ushort_t* x2 = x1 + XSZ;
    ushort_t* x3 = x2 + XSZ;
    ushort_t* Wt = x3 + XSZ;                      // 4*128*128
    int* iw      = (int*)(Wt + 4 * 128 * 128);
    int* row_ptr = iw;                            // V+1
    int* counts  = iw + 50016;
    int* nxt     = iw + 100032;
    int* blk_sums= iw + 150048;                   // 49 used (64 reserved)
    int* blk_off = iw + 150112;                   // 49 used (64 reserved)
    int2* edges  = (int2*)(iw + 150176);          // E packed {col, val}
    // total ws ~ 212 MB

    // 1) transpose input -> x0 (bf16)
    dim3 tgrid((V_N + 127) / 128, F_N / 32);
    k_transpose_in<<<tgrid, 256, 0, stream>>>(x, x0);

    // 2) CSR build
    hipMemsetAsync(counts, 0, V_N * sizeof(int), stream);
    k_hist<<<(E_N + 255) / 256, 256, 0, stream>>>(edge_row, counts);
    k_scan_blk<<<SCAN_NB, 256, 0, stream>>>(counts, row_ptr, blk_sums);
    k_scan_top<<<1, 64, 0, stream>>>(blk_sums, blk_off);
    k_scan_add<<<SCAN_NB, 256, 0, stream>>>(blk_off, row_ptr, nxt);
    k_scatter<<<(E_N + 255) / 256, 256, 0, stream>>>(edge_row, edge_col, edge_val,
                                                     nxt, edges);

    // 3) weights -> bf16, Chebyshev-folded, transposed to (k, o, c)
    k_wprep<<<64, 256, 0, stream>>>(weights, Wt);

    // 4) Pure power chain z_k = A z_{k-1} (bf16 state, fp32 accumulate)
    //    grid: bid = rowblock*2 + half -> XCD parity pins the feature half
    k_spmm_bf16<<<V_N * 2 / 4, 256, 0, stream>>>(row_ptr, edges, x0, x1);
    k_spmm_bf16<<<V_N * 2 / 4, 256, 0, stream>>>(row_ptr, edges, x1, x2);
    k_spmm_bf16<<<V_N * 2 / 4, 256, 0, stream>>>(row_ptr, edges, x2, x3);

    // 5) fused MFMA GEMM (folded weights) + bias + transpose to (B,Cout,V)
    k_gemm_mfma<<<(M_TOT + 127) / 128, 256, 0, stream>>>(x0, x1, x2, x3, Wt,
                                                         biases, out);
}

// Round 10
// 676.493 us; speedup vs baseline: 1.1541x; 1.0146x over previous
//
#include <hip/hip_runtime.h>

// Problem constants (fixed by the reference setup_inputs)
#define V_N   50000
#define B_N   4
#define C_IN  128
#define C_OUT 128
#define E_N   800000
#define F_N   512                 // B_N * C_IN features per vertex
#define M_TOT 200000              // V_N * B_N rows of the (v,b) GEMM view

#define SCAN_BLK  1024                        // elements per scan block (256 thr x 4)
#define SCAN_NB   ((V_N + SCAN_BLK - 1) / SCAN_BLK)   // 49

// fused prep-kernel block ranges
#define NTB_V   ((V_N + 127) / 128)           // 391 transpose v-blocks
#define NTB     (NTB_V * 16)                  // 6256 transpose blocks
#define NHB     ((E_N + 255) / 256)           // 3125 hist blocks
#define NWB     64                            // wprep blocks
#define NPREP   (NTB + NHB + NWB)             // 9445

typedef unsigned short ushort_t;
typedef __attribute__((ext_vector_type(8))) short short8;   // 8 bf16 (4 VGPRs)
typedef __attribute__((ext_vector_type(4))) float f32x4;

#define AS1 __attribute__((address_space(1)))
#define AS3 __attribute__((address_space(3)))
// async global->LDS DMA, 16 B per lane. LDS dest: wave-uniform base + lane*16.
__device__ __forceinline__ void gl_lds16(const void* gp, void* lp) {
    __builtin_amdgcn_global_load_lds((const AS1 unsigned int*)gp,
                                     (AS3 unsigned int*)lp, 16, 0, 0);
}

__device__ __forceinline__ float bf_lo(unsigned u) { return __uint_as_float(u << 16); }
__device__ __forceinline__ float bf_hi(unsigned u) { return __uint_as_float(u & 0xFFFF0000u); }
__device__ __forceinline__ ushort_t f2bf(float f) {      // RNE
    unsigned u = __float_as_uint(f);
    u += 0x7FFFu + ((u >> 16) & 1u);
    return (ushort_t)(u >> 16);
}

// ---------------------------------------------------------------------------
// 1) Fused prep: three independent jobs routed by block range.
//    [0, NTB)          transpose x (B,Cin,V) fp32 -> x0 (V,F) bf16
//    [NTB, NTB+NHB)    histogram of edge_row into counts
//    [NTB+NHB, NPREP)  Chebyshev-folded weight prep -> Wt (k,o,c) bf16
//    Disjoint in/out sets; fusing packs the machine instead of serializing.
// ---------------------------------------------------------------------------
__global__ __launch_bounds__(256) void k_prep(const float* __restrict__ x,
                                              ushort_t* __restrict__ x0,
                                              const int* __restrict__ edge_row,
                                              int* __restrict__ counts,
                                              const float* __restrict__ W,
                                              ushort_t* __restrict__ Wt) {
    __shared__ float tile[32][133];   // [f][v] (transpose branch only)
    int b = blockIdx.x;
    int tid = threadIdx.x;

    if (b < NTB) {
        // ---- transpose: float4 reads, LDS tile, uint2 bf16 writes ----
        int vb = (b % NTB_V) * 128;
        int fb = (b / NTB_V) * 32;
        int fo = tid >> 5;               // 0..7
        int vo = (tid & 31) * 4;         // 0..124
#pragma unroll
        for (int p = 0; p < 4; p++) {
            int f = fb + fo + p * 8;
            int v = vb + vo;
            float4 val = make_float4(0.f, 0.f, 0.f, 0.f);
            const float* xp = &x[(size_t)f * V_N + v];
            if (v + 3 < V_N) {
                val = *(const float4*)xp;
            } else {
                if (v     < V_N) val.x = xp[0];
                if (v + 1 < V_N) val.y = xp[1];
                if (v + 2 < V_N) val.z = xp[2];
                if (v + 3 < V_N) val.w = xp[3];
            }
            tile[fo + p * 8][vo + 0] = val.x;
            tile[fo + p * 8][vo + 1] = val.y;
            tile[fo + p * 8][vo + 2] = val.z;
            tile[fo + p * 8][vo + 3] = val.w;
        }
        __syncthreads();
        int fl = (tid & 7) * 4;          // 0,4,..,28
        int vbase = tid >> 3;            // 0..31
#pragma unroll
        for (int i = 0; i < 4; i++) {
            int vloc = vbase + i * 32;
            int v = vb + vloc;
            if (v < V_N) {
                ushort_t r[4] = { f2bf(tile[fl + 0][vloc]), f2bf(tile[fl + 1][vloc]),
                                  f2bf(tile[fl + 2][vloc]), f2bf(tile[fl + 3][vloc]) };
                *(uint2*)&x0[(size_t)v * F_N + fb + fl] = *(const uint2*)r;
            }
        }
    } else if (b < NTB + NHB) {
        // ---- histogram ----
        int e = (b - NTB) * 256 + tid;
        if (e < E_N) atomicAdd(&counts[edge_row[e]], 1);
    } else {
        // ---- weight prep, Chebyshev folding:
        //      T0=I, T1=A, T2=2A^2-I, T3=4A^3-3A =>
        //      z0(W0-W2) + z1(W1-3W3) + z2(2W2) + z3(4W3) ----
        int i = (b - NTB - NHB) * 256 + tid;      // 16384 total: (c,o)
        int c = i >> 7, o = i & 127;
        float w0 = W[0 * 16384 + c * 128 + o];
        float w1 = W[1 * 16384 + c * 128 + o];
        float w2 = W[2 * 16384 + c * 128 + o];
        float w3 = W[3 * 16384 + c * 128 + o];
        Wt[((size_t)0 * 128 + o) * 128 + c] = f2bf(w0 - w2);
        Wt[((size_t)1 * 128 + o) * 128 + c] = f2bf(w1 - 3.f * w3);
        Wt[((size_t)2 * 128 + o) * 128 + c] = f2bf(2.f * w2);
        Wt[((size_t)3 * 128 + o) * 128 + c] = f2bf(4.f * w3);
    }
}

// ---------------------------------------------------------------------------
// 2) CSR build: scan stage 1 -> fused offset+add stage -> scatter
// ---------------------------------------------------------------------------
__global__ __launch_bounds__(256) void k_scan_blk(const int* __restrict__ counts,
                                                  int* __restrict__ row_ptr,
                                                  int* __restrict__ blk_sums) {
    __shared__ int s[256];
    int t = threadIdx.x;
    int base = blockIdx.x * SCAN_BLK + t * 4;
    int c0 = (base + 0 < V_N) ? counts[base + 0] : 0;
    int c1 = (base + 1 < V_N) ? counts[base + 1] : 0;
    int c2 = (base + 2 < V_N) ? counts[base + 2] : 0;
    int c3 = (base + 3 < V_N) ? counts[base + 3] : 0;
    int p1 = c0, p2 = c0 + c1, p3 = c0 + c1 + c2, tot = p3 + c3;
    s[t] = tot;
    __syncthreads();
#pragma unroll
    for (int off = 1; off < 256; off <<= 1) {
        int v = (t >= off) ? s[t - off] : 0;
        __syncthreads();
        s[t] += v;
        __syncthreads();
    }
    int excl = (t == 0) ? 0 : s[t - 1];
    if (base + 0 < V_N) row_ptr[base + 0] = excl;
    if (base + 1 < V_N) row_ptr[base + 1] = excl + p1;
    if (base + 2 < V_N) row_ptr[base + 2] = excl + p2;
    if (base + 3 < V_N) row_ptr[base + 3] = excl + p3;
    if (t == 255) blk_sums[blockIdx.x] = s[255];
}

// Stage 2+3 fused: each block re-derives its global offset from blk_sums
// (49 loads + wave reduce), adds it, mirrors into next[], writes row_ptr[V].
__global__ __launch_bounds__(256) void k_scan_add(const int* __restrict__ blk_sums,
                                                  int* __restrict__ row_ptr,
                                                  int* __restrict__ next) {
    __shared__ int off_s, tot_s;
    int b = blockIdx.x, t = threadIdx.x;
    if (t < 64) {
        int v  = (t < SCAN_NB) ? blk_sums[t] : 0;
        int pv = (t < b) ? v : 0;
#pragma unroll
        for (int o = 32; o; o >>= 1) {
            pv += __shfl_down(pv, o);
            v  += __shfl_down(v, o);
        }
        if (t == 0) { off_s = pv; tot_s = v; }
    }
    __syncthreads();
    int off = off_s;
    int base = b * SCAN_BLK + t * 4;
#pragma unroll
    for (int i = 0; i < 4; i++) {
        int idx = base + i;
        if (idx < V_N) {
            int rv = row_ptr[idx] + off;
            row_ptr[idx] = rv;
            next[idx]    = rv;
        }
    }
    if (b == 0 && t == 0) row_ptr[V_N] = tot_s;
}

__global__ __launch_bounds__(256) void k_scatter(const int* __restrict__ row,
                                                 const int* __restrict__ col,
                                                 const float* __restrict__ vals,
                                                 int* __restrict__ next,
                                                 int2* __restrict__ edges) {
    int e = blockIdx.x * blockDim.x + threadIdx.x;
    if (e < E_N) {
        int r = row[e];
        int pos = atomicAdd(&next[r], 1);
        edges[pos] = make_int2(col[e], __float_as_int(vals[e]));
    }
}

// ---------------------------------------------------------------------------
// 4) Pure-power SpMM (bf16, fp32 accumulate): dst = A * src.  ROUND-8 EXACT —
//    empirical floor (112.5us) across 5 structural/locality variants
//    (r3 wave-per-row, r4 feature-chunk, r5 bucket-sort, r6 quarter-pin,
//    r9 half-pin+NT). Fetch cuts don't cut time: request-stream-bound.
// ---------------------------------------------------------------------------
__global__ __launch_bounds__(256) void k_spmm_bf16(const int* __restrict__ row_ptr,
                                                   const int2* __restrict__ edges,
                                                   const ushort_t* __restrict__ src,
                                                   ushort_t* __restrict__ dst) {
    int lane = threadIdx.x & 63;
    int g = blockIdx.x * 4 + (threadIdx.x >> 6);   // global wave id
    int r = g >> 1;
    int h = g & 1;                                  // feature half
    int e0 = row_ptr[r], e1 = row_ptr[r + 1];
    float a0 = 0.f, a1 = 0.f, a2 = 0.f, a3 = 0.f;
    const ushort_t* sp = src + h * 256 + lane * 4;

    int e = e0;
    for (; e + 4 <= e1; e += 4) {
        int2 E0 = edges[e], E1 = edges[e + 1], E2 = edges[e + 2], E3 = edges[e + 3];
        uint2 g0 = *(const uint2*)(sp + (size_t)E0.x * F_N);
        uint2 g1 = *(const uint2*)(sp + (size_t)E1.x * F_N);
        uint2 g2 = *(const uint2*)(sp + (size_t)E2.x * F_N);
        uint2 g3 = *(const uint2*)(sp + (size_t)E3.x * F_N);
        float w0 = __int_as_float(E0.y), w1 = __int_as_float(E1.y);
        float w2 = __int_as_float(E2.y), w3 = __int_as_float(E3.y);
        a0 += w0 * bf_lo(g0.x); a1 += w0 * bf_hi(g0.x);
        a2 += w0 * bf_lo(g0.y); a3 += w0 * bf_hi(g0.y);
        a0 += w1 * bf_lo(g1.x); a1 += w1 * bf_hi(g1.x);
        a2 += w1 * bf_lo(g1.y); a3 += w1 * bf_hi(g1.y);
        a0 += w2 * bf_lo(g2.x); a1 += w2 * bf_hi(g2.x);
        a2 += w2 * bf_lo(g2.y); a3 += w2 * bf_hi(g2.y);
        a0 += w3 * bf_lo(g3.x); a1 += w3 * bf_hi(g3.x);
        a2 += w3 * bf_lo(g3.y); a3 += w3 * bf_hi(g3.y);
    }
    for (; e < e1; e++) {
        int2 E = edges[e];
        uint2 gv = *(const uint2*)(sp + (size_t)E.x * F_N);
        float w = __int_as_float(E.y);
        a0 += w * bf_lo(gv.x); a1 += w * bf_hi(gv.x);
        a2 += w * bf_lo(gv.y); a3 += w * bf_hi(gv.y);
    }

    size_t off = (size_t)r * F_N + h * 256 + lane * 4;
    ushort_t res[4] = {f2bf(a0), f2bf(a1), f2bf(a2), f2bf(a3)};
    *(uint2*)(dst + off) = *(const uint2*)res;
}

// ---------------------------------------------------------------------------
// 5) MFMA GEMM over the 4 power-states with folded weights, fused bias +
//    output transpose.  m97-style: global_load_lds 16B DMA, BK=64, XOR
//    chunk-swizzle both-sides.
// ---------------------------------------------------------------------------
__global__ __launch_bounds__(256, 2) void k_gemm_mfma(
        const ushort_t* __restrict__ X0, const ushort_t* __restrict__ X1,
        const ushort_t* __restrict__ X2, const ushort_t* __restrict__ X3,
        const ushort_t* __restrict__ Wt, const float* __restrict__ bias,
        float* __restrict__ out) {
    __shared__ ushort_t As[128][64];   // linear (DMA dest), 16 KB
    __shared__ ushort_t Bs[128][64];   // linear (DMA dest), 16 KB
    __shared__ float    Cs[64][133];   // epilogue transpose staging, 34 KB

    int tid  = threadIdx.x;
    int lane = tid & 63;
    int wv   = tid >> 6;
    int wm = wv >> 1, wn = wv & 1;
    int quad = lane >> 4, l15 = lane & 15;
    int m_blk = blockIdx.x * 128;

    f32x4 acc[4][4];
#pragma unroll
    for (int fi = 0; fi < 4; fi++)
#pragma unroll
        for (int fj = 0; fj < 4; fj++) {
            acc[fi][fj][0] = 0.f; acc[fi][fj][1] = 0.f;
            acc[fi][fj][2] = 0.f; acc[fi][fj][3] = 0.f;
        }

    const ushort_t* Xb[4] = {X0, X1, X2, X3};

    // staging geometry: one DMA inst = 64 lanes x 16 B = 1 KB = 8 rows of 128 B.
    int rr_s = lane >> 3;              // row within 8-row group
    int pl   = lane & 7;               // 16B chunk slot within row (LDS side)
    for (int kb = 0; kb < 4; kb++) {
        const ushort_t* A = Xb[kb];
        const ushort_t* W = Wt + (size_t)kb * (128 * 128);
        for (int kk = 0; kk < 128; kk += 64) {
            __syncthreads();           // previous step's ds_reads done
#pragma unroll
            for (int i = 0; i < 4; i++) {
                int r0 = (wv * 4 + i) * 8;           // wave-uniform
                int rr = r0 + rr_s;
                int pg = pl ^ (rr & 7);              // pre-swizzled source chunk
                int gm = m_blk + rr; if (gm >= M_TOT) gm = M_TOT - 1;
                gl_lds16(&A[(size_t)gm * 128 + kk + pg * 8], &As[r0][0]);
                gl_lds16(&W[(size_t)rr * 128 + kk + pg * 8], &Bs[r0][0]);
            }
            __syncthreads();           // drains vmcnt -> tiles ready

            short8 a[2][4], b[2][4];
#pragma unroll
            for (int h = 0; h < 2; h++)
#pragma unroll
                for (int f = 0; f < 4; f++) {
                    int ra = wm * 64 + f * 16 + l15;
                    int ca = (h * 4 + quad) ^ (ra & 7);
                    a[h][f] = *(const short8*)&As[ra][ca * 8];
                    int rb = wn * 64 + f * 16 + l15;
                    int cb = (h * 4 + quad) ^ (rb & 7);
                    b[h][f] = *(const short8*)&Bs[rb][cb * 8];
                }
#pragma unroll
            for (int h = 0; h < 2; h++)
#pragma unroll
                for (int fi = 0; fi < 4; fi++)
#pragma unroll
                    for (int fj = 0; fj < 4; fj++)
                        acc[fi][fj] = __builtin_amdgcn_mfma_f32_16x16x32_bf16(
                            a[h][fi], b[h][fj], acc[fi][fj], 0, 0, 0);
        }
    }

    // epilogue: 2 chunks of 64 m-rows -> LDS -> transposed global store
    int v_blk = m_blk >> 2;
    for (int h = 0; h < 2; h++) {
        __syncthreads();
        if (wm == h) {
#pragma unroll
            for (int fi = 0; fi < 4; fi++)
#pragma unroll
                for (int fj = 0; fj < 4; fj++) {
                    int ml = fi * 16 + quad * 4;
                    int n  = wn * 64 + fj * 16 + l15;
#pragma unroll
                    for (int reg = 0; reg < 4; reg++)
                        Cs[ml + reg][n] = acc[fi][fj][reg];
                }
        }
        __syncthreads();
#pragma unroll
        for (int i = 0; i < 8; i++) {
            int idx = tid + i * 256;          // 0..2047
            int v4  = idx & 3;                // float4-chunk of v
            int o   = (idx >> 2) & 127;
            int b   = idx >> 9;               // 0..3
            int vl  = v4 * 4;
            float bv = bias[o];
            float r0 = Cs[(vl + 0) * 4 + b][o] + bv;
            float r1 = Cs[(vl + 1) * 4 + b][o] + bv;
            float r2 = Cs[(vl + 2) * 4 + b][o] + bv;
            float r3 = Cs[(vl + 3) * 4 + b][o] + bv;
            int v0 = v_blk + h * 16 + vl;
            float* op = out + ((size_t)b * C_OUT + o) * V_N + v0;
            if (v0 + 3 < V_N) {
                *(float4*)op = make_float4(r0, r1, r2, r3);
            } else {
                if (v0     < V_N) op[0] = r0;
                if (v0 + 1 < V_N) op[1] = r1;
                if (v0 + 2 < V_N) op[2] = r2;
                if (v0 + 3 < V_N) op[3] = r3;
            }
        }
    }
}

// ---------------------------------------------------------------------------
extern "C" void kernel_launch(void* const* d_in, const int* in_sizes, int n_in,
                              void* d_out, int out_size, void* d_ws, size_t ws_size,
                              hipStream_t stream) {
    const float* x        = (const float*)d_in[0];
    const int*   edge_row = (const int*)  d_in[1];
    const int*   edge_col = (const int*)  d_in[2];
    const float* edge_val = (const float*)d_in[3];
    const float* weights  = (const float*)d_in[4];
    const float* biases   = (const float*)d_in[5];
    float* out = (float*)d_out;

    // workspace layout: x0..x3 (bf16, V*F each) | Wt (bf16) | int arrays | edges
    const size_t XSZ = (size_t)V_N * F_N;         // 25.6M elements
    ushort_t* x0 = (ushort_t*)d_ws;
    ushort_t* x1 = x0 + XSZ;
    ushort_t* x2 = x1 + XSZ;
    ushort_t* x3 = x2 + XSZ;
    ushort_t* Wt = x3 + XSZ;                      // 4*128*128
    int* iw      = (int*)(Wt + 4 * 128 * 128);
    int* row_ptr = iw;                            // V+1
    int* counts  = iw + 50016;
    int* nxt     = iw + 100032;
    int* blk_sums= iw + 150048;                   // 49 used (64 reserved)
    int2* edges  = (int2*)(iw + 150176);          // E packed {col, val}
    // total ws ~ 212 MB

    // 1) fused prep: transpose -> x0 | histogram -> counts | weights -> Wt
    hipMemsetAsync(counts, 0, V_N * sizeof(int), stream);
    k_prep<<<NPREP, 256, 0, stream>>>(x, x0, edge_row, counts, weights, Wt);

    // 2) CSR scan + scatter
    k_scan_blk<<<SCAN_NB, 256, 0, stream>>>(counts, row_ptr, blk_sums);
    k_scan_add<<<SCAN_NB, 256, 0, stream>>>(blk_sums, row_ptr, nxt);
    k_scatter<<<(E_N + 255) / 256, 256, 0, stream>>>(edge_row, edge_col, edge_val,
                                                     nxt, edges);

    // 3) Pure power chain z_k = A z_{k-1} (bf16 state, fp32 accumulate)
    k_spmm_bf16<<<V_N * 2 / 4, 256, 0, stream>>>(row_ptr, edges, x0, x1);
    k_spmm_bf16<<<V_N * 2 / 4, 256, 0, stream>>>(row_ptr, edges, x1, x2);
    k_spmm_bf16<<<V_N * 2 / 4, 256, 0, stream>>>(row_ptr, edges, x2, x3);

    // 4) fused MFMA GEMM (folded weights) + bias + transpose to (B,Cout,V)
    k_gemm_mfma<<<(M_TOT + 127) / 128, 256, 0, stream>>>(x0, x1, x2, x3, Wt,
                                                         biases, out);
}

// Round 11
// 674.557 us; speedup vs baseline: 1.1574x; 1.0029x over previous
//
#include <hip/hip_runtime.h>

// Problem constants (fixed by the reference setup_inputs)
#define V_N   50000
#define B_N   4
#define C_IN  128
#define C_OUT 128
#define E_N   800000
#define F_N   512                 // B_N * C_IN features per vertex
#define M_TOT 200000              // V_N * B_N rows of the (v,b) GEMM view

#define SCAN_BLK  1024                        // elements per scan block (256 thr x 4)
#define SCAN_NB   ((V_N + SCAN_BLK - 1) / SCAN_BLK)   // 49

// fused prep-kernel block ranges
#define NTB_V   ((V_N + 127) / 128)           // 391 transpose v-blocks
#define NTB     (NTB_V * 16)                  // 6256 transpose blocks
#define NHB     ((E_N + 255) / 256)           // 3125 hist blocks
#define NWB     64                            // wprep blocks
#define NPREP   (NTB + NHB + NWB)             // 9445

typedef unsigned short ushort_t;
typedef __attribute__((ext_vector_type(8))) short short8;   // 8 bf16 (4 VGPRs)
typedef __attribute__((ext_vector_type(4))) float f32x4;

#define AS1 __attribute__((address_space(1)))
#define AS3 __attribute__((address_space(3)))
// async global->LDS DMA, 16 B per lane. LDS dest: wave-uniform base + lane*16.
__device__ __forceinline__ void gl_lds16(const void* gp, void* lp) {
    __builtin_amdgcn_global_load_lds((const AS1 unsigned int*)gp,
                                     (AS3 unsigned int*)lp, 16, 0, 0);
}

__device__ __forceinline__ float bf_lo(unsigned u) { return __uint_as_float(u << 16); }
__device__ __forceinline__ float bf_hi(unsigned u) { return __uint_as_float(u & 0xFFFF0000u); }
__device__ __forceinline__ ushort_t f2bf(float f) {      // RNE
    unsigned u = __float_as_uint(f);
    u += 0x7FFFu + ((u >> 16) & 1u);
    return (ushort_t)(u >> 16);
}

// ---------------------------------------------------------------------------
// 1) Fused prep: three independent jobs routed by block range.
//    [0, NTB)          transpose x (B,Cin,V) fp32 -> x0 (V,F) bf16
//    [NTB, NTB+NHB)    histogram of edge_row into counts
//    [NTB+NHB, NPREP)  Chebyshev-folded weight prep -> Wt (k,o,c) bf16
// ---------------------------------------------------------------------------
__global__ __launch_bounds__(256) void k_prep(const float* __restrict__ x,
                                              ushort_t* __restrict__ x0,
                                              const int* __restrict__ edge_row,
                                              int* __restrict__ counts,
                                              const float* __restrict__ W,
                                              ushort_t* __restrict__ Wt) {
    __shared__ float tile[32][133];   // [f][v] (transpose branch only)
    int b = blockIdx.x;
    int tid = threadIdx.x;

    if (b < NTB) {
        // ---- transpose: float4 reads, LDS tile, uint2 bf16 writes ----
        int vb = (b % NTB_V) * 128;
        int fb = (b / NTB_V) * 32;
        int fo = tid >> 5;               // 0..7
        int vo = (tid & 31) * 4;         // 0..124
#pragma unroll
        for (int p = 0; p < 4; p++) {
            int f = fb + fo + p * 8;
            int v = vb + vo;
            float4 val = make_float4(0.f, 0.f, 0.f, 0.f);
            const float* xp = &x[(size_t)f * V_N + v];
            if (v + 3 < V_N) {
                val = *(const float4*)xp;
            } else {
                if (v     < V_N) val.x = xp[0];
                if (v + 1 < V_N) val.y = xp[1];
                if (v + 2 < V_N) val.z = xp[2];
                if (v + 3 < V_N) val.w = xp[3];
            }
            tile[fo + p * 8][vo + 0] = val.x;
            tile[fo + p * 8][vo + 1] = val.y;
            tile[fo + p * 8][vo + 2] = val.z;
            tile[fo + p * 8][vo + 3] = val.w;
        }
        __syncthreads();
        int fl = (tid & 7) * 4;          // 0,4,..,28
        int vbase = tid >> 3;            // 0..31
#pragma unroll
        for (int i = 0; i < 4; i++) {
            int vloc = vbase + i * 32;
            int v = vb + vloc;
            if (v < V_N) {
                ushort_t r[4] = { f2bf(tile[fl + 0][vloc]), f2bf(tile[fl + 1][vloc]),
                                  f2bf(tile[fl + 2][vloc]), f2bf(tile[fl + 3][vloc]) };
                *(uint2*)&x0[(size_t)v * F_N + fb + fl] = *(const uint2*)r;
            }
        }
    } else if (b < NTB + NHB) {
        // ---- histogram ----
        int e = (b - NTB) * 256 + tid;
        if (e < E_N) atomicAdd(&counts[edge_row[e]], 1);
    } else {
        // ---- weight prep, Chebyshev folding:
        //      z0(W0-W2) + z1(W1-3W3) + z2(2W2) + z3(4W3) ----
        int i = (b - NTB - NHB) * 256 + tid;      // 16384 total: (c,o)
        int c = i >> 7, o = i & 127;
        float w0 = W[0 * 16384 + c * 128 + o];
        float w1 = W[1 * 16384 + c * 128 + o];
        float w2 = W[2 * 16384 + c * 128 + o];
        float w3 = W[3 * 16384 + c * 128 + o];
        Wt[((size_t)0 * 128 + o) * 128 + c] = f2bf(w0 - w2);
        Wt[((size_t)1 * 128 + o) * 128 + c] = f2bf(w1 - 3.f * w3);
        Wt[((size_t)2 * 128 + o) * 128 + c] = f2bf(2.f * w2);
        Wt[((size_t)3 * 128 + o) * 128 + c] = f2bf(4.f * w3);
    }
}

// ---------------------------------------------------------------------------
// 2) CSR build: scan stage 1 -> fused offset+add stage -> scatter
// ---------------------------------------------------------------------------
__global__ __launch_bounds__(256) void k_scan_blk(const int* __restrict__ counts,
                                                  int* __restrict__ row_ptr,
                                                  int* __restrict__ blk_sums) {
    __shared__ int s[256];
    int t = threadIdx.x;
    int base = blockIdx.x * SCAN_BLK + t * 4;
    int c0 = (base + 0 < V_N) ? counts[base + 0] : 0;
    int c1 = (base + 1 < V_N) ? counts[base + 1] : 0;
    int c2 = (base + 2 < V_N) ? counts[base + 2] : 0;
    int c3 = (base + 3 < V_N) ? counts[base + 3] : 0;
    int p1 = c0, p2 = c0 + c1, p3 = c0 + c1 + c2, tot = p3 + c3;
    s[t] = tot;
    __syncthreads();
#pragma unroll
    for (int off = 1; off < 256; off <<= 1) {
        int v = (t >= off) ? s[t - off] : 0;
        __syncthreads();
        s[t] += v;
        __syncthreads();
    }
    int excl = (t == 0) ? 0 : s[t - 1];
    if (base + 0 < V_N) row_ptr[base + 0] = excl;
    if (base + 1 < V_N) row_ptr[base + 1] = excl + p1;
    if (base + 2 < V_N) row_ptr[base + 2] = excl + p2;
    if (base + 3 < V_N) row_ptr[base + 3] = excl + p3;
    if (t == 255) blk_sums[blockIdx.x] = s[255];
}

// Stage 2+3 fused: each block re-derives its global offset from blk_sums.
__global__ __launch_bounds__(256) void k_scan_add(const int* __restrict__ blk_sums,
                                                  int* __restrict__ row_ptr,
                                                  int* __restrict__ next) {
    __shared__ int off_s, tot_s;
    int b = blockIdx.x, t = threadIdx.x;
    if (t < 64) {
        int v  = (t < SCAN_NB) ? blk_sums[t] : 0;
        int pv = (t < b) ? v : 0;
#pragma unroll
        for (int o = 32; o; o >>= 1) {
            pv += __shfl_down(pv, o);
            v  += __shfl_down(v, o);
        }
        if (t == 0) { off_s = pv; tot_s = v; }
    }
    __syncthreads();
    int off = off_s;
    int base = b * SCAN_BLK + t * 4;
#pragma unroll
    for (int i = 0; i < 4; i++) {
        int idx = base + i;
        if (idx < V_N) {
            int rv = row_ptr[idx] + off;
            row_ptr[idx] = rv;
            next[idx]    = rv;
        }
    }
    if (b == 0 && t == 0) row_ptr[V_N] = tot_s;
}

__global__ __launch_bounds__(256) void k_scatter(const int* __restrict__ row,
                                                 const int* __restrict__ col,
                                                 const float* __restrict__ vals,
                                                 int* __restrict__ next,
                                                 int2* __restrict__ edges) {
    int e = blockIdx.x * blockDim.x + threadIdx.x;
    if (e < E_N) {
        int r = row[e];
        int pos = atomicAdd(&next[r], 1);
        edges[pos] = make_int2(col[e], __float_as_int(vals[e]));
    }
}

// ---------------------------------------------------------------------------
// 4) Pure-power SpMM (bf16, fp32 accumulate): dst = A * src.  ROUND-8 EXACT —
//    empirical floor (112.5us) across 5 structural/locality variants.
// ---------------------------------------------------------------------------
__global__ __launch_bounds__(256) void k_spmm_bf16(const int* __restrict__ row_ptr,
                                                   const int2* __restrict__ edges,
                                                   const ushort_t* __restrict__ src,
                                                   ushort_t* __restrict__ dst) {
    int lane = threadIdx.x & 63;
    int g = blockIdx.x * 4 + (threadIdx.x >> 6);   // global wave id
    int r = g >> 1;
    int h = g & 1;                                  // feature half
    int e0 = row_ptr[r], e1 = row_ptr[r + 1];
    float a0 = 0.f, a1 = 0.f, a2 = 0.f, a3 = 0.f;
    const ushort_t* sp = src + h * 256 + lane * 4;

    int e = e0;
    for (; e + 4 <= e1; e += 4) {
        int2 E0 = edges[e], E1 = edges[e + 1], E2 = edges[e + 2], E3 = edges[e + 3];
        uint2 g0 = *(const uint2*)(sp + (size_t)E0.x * F_N);
        uint2 g1 = *(const uint2*)(sp + (size_t)E1.x * F_N);
        uint2 g2 = *(const uint2*)(sp + (size_t)E2.x * F_N);
        uint2 g3 = *(const uint2*)(sp + (size_t)E3.x * F_N);
        float w0 = __int_as_float(E0.y), w1 = __int_as_float(E1.y);
        float w2 = __int_as_float(E2.y), w3 = __int_as_float(E3.y);
        a0 += w0 * bf_lo(g0.x); a1 += w0 * bf_hi(g0.x);
        a2 += w0 * bf_lo(g0.y); a3 += w0 * bf_hi(g0.y);
        a0 += w1 * bf_lo(g1.x); a1 += w1 * bf_hi(g1.x);
        a2 += w1 * bf_lo(g1.y); a3 += w1 * bf_hi(g1.y);
        a0 += w2 * bf_lo(g2.x); a1 += w2 * bf_hi(g2.x);
        a2 += w2 * bf_lo(g2.y); a3 += w2 * bf_hi(g2.y);
        a0 += w3 * bf_lo(g3.x); a1 += w3 * bf_hi(g3.x);
        a2 += w3 * bf_lo(g3.y); a3 += w3 * bf_hi(g3.y);
    }
    for (; e < e1; e++) {
        int2 E = edges[e];
        uint2 gv = *(const uint2*)(sp + (size_t)E.x * F_N);
        float w = __int_as_float(E.y);
        a0 += w * bf_lo(gv.x); a1 += w * bf_hi(gv.x);
        a2 += w * bf_lo(gv.y); a3 += w * bf_hi(gv.y);
    }

    size_t off = (size_t)r * F_N + h * 256 + lane * 4;
    ushort_t res[4] = {f2bf(a0), f2bf(a1), f2bf(a2), f2bf(a3)};
    *(uint2*)(dst + off) = *(const uint2*)res;
}

// ---------------------------------------------------------------------------
// 5) MFMA GEMM, T3 2-phase pipelined: double-buffered LDS, STAGE one step
//    ahead, single __syncthreads per step (its implicit vmcnt drain is the
//    pipeline wait) -> DMA latency hides under ds_read+MFMA. 8 steps, 9
//    barriers (was 16 exposed-latency stalls + 16 barriers). Epilogue Cs
//    aliases the dead pipeline buffers -> LDS stays 64 KB, 2 blocks/CU.
// ---------------------------------------------------------------------------
__global__ __launch_bounds__(256, 2) void k_gemm_mfma(
        const ushort_t* __restrict__ X0, const ushort_t* __restrict__ X1,
        const ushort_t* __restrict__ X2, const ushort_t* __restrict__ X3,
        const ushort_t* __restrict__ Wt, const float* __restrict__ bias,
        float* __restrict__ out) {
    // [buf][A=0/B=1][row][col] : 2*2*128*64*2B = 64 KB
    __shared__ __align__(16) ushort_t smem[2][2][128][64];

    int tid  = threadIdx.x;
    int lane = tid & 63;
    int wv   = tid >> 6;
    int wm = wv >> 1, wn = wv & 1;
    int quad = lane >> 4, l15 = lane & 15;
    int m_blk = blockIdx.x * 128;

    f32x4 acc[4][4];
#pragma unroll
    for (int fi = 0; fi < 4; fi++)
#pragma unroll
        for (int fj = 0; fj < 4; fj++) {
            acc[fi][fj][0] = 0.f; acc[fi][fj][1] = 0.f;
            acc[fi][fj][2] = 0.f; acc[fi][fj][3] = 0.f;
        }

    const ushort_t* Xb[4] = {X0, X1, X2, X3};

    // staging geometry: one DMA inst = 64 lanes x 16 B = 1 KB = 8 rows of 128 B.
    int rr_s = lane >> 3;              // row within 8-row group
    int pl   = lane & 7;               // 16B chunk slot within row (LDS side)

    // stage step s (s = 0..7: kb = s>>1, kk = (s&1)*64) into buffer bf
#define STAGE_STEP(s, bf)                                                     \
    {                                                                         \
        const ushort_t* A_ = Xb[(s) >> 1];                                    \
        const ushort_t* W_ = Wt + (size_t)((s) >> 1) * (128 * 128);           \
        int kk_ = ((s) & 1) * 64;                                             \
        _Pragma("unroll")                                                     \
        for (int i = 0; i < 4; i++) {                                         \
            int r0 = (wv * 4 + i) * 8;                                        \
            int rr = r0 + rr_s;                                               \
            int pg = pl ^ (rr & 7);                                           \
            int gm = m_blk + rr; if (gm >= M_TOT) gm = M_TOT - 1;             \
            gl_lds16(&A_[(size_t)gm * 128 + kk_ + pg * 8], &smem[bf][0][r0][0]); \
            gl_lds16(&W_[(size_t)rr * 128 + kk_ + pg * 8], &smem[bf][1][r0][0]); \
        }                                                                     \
    }

    STAGE_STEP(0, 0);
    __syncthreads();                   // buf0 ready (implicit vmcnt drain)

    for (int s = 0; s < 8; s++) {
        int bf = s & 1;
        if (s < 7) STAGE_STEP(s + 1, bf ^ 1);   // prefetch next step

        short8 a[2][4], b[2][4];
#pragma unroll
        for (int h = 0; h < 2; h++)
#pragma unroll
            for (int f = 0; f < 4; f++) {
                int ra = wm * 64 + f * 16 + l15;
                int ca = (h * 4 + quad) ^ (ra & 7);
                a[h][f] = *(const short8*)&smem[bf][0][ra][ca * 8];
                int rb = wn * 64 + f * 16 + l15;
                int cb = (h * 4 + quad) ^ (rb & 7);
                b[h][f] = *(const short8*)&smem[bf][1][rb][cb * 8];
            }
#pragma unroll
        for (int h = 0; h < 2; h++)
#pragma unroll
            for (int fi = 0; fi < 4; fi++)
#pragma unroll
                for (int fj = 0; fj < 4; fj++)
                    acc[fi][fj] = __builtin_amdgcn_mfma_f32_16x16x32_bf16(
                        a[h][fi], b[h][fj], acc[fi][fj], 0, 0, 0);

        __syncthreads();   // drains next-step DMA + all waves' reads of buf
    }
#undef STAGE_STEP

    // epilogue: Cs aliases the (dead) pipeline buffers. 64x133 f32 = 34 KB.
    float* Cs = (float*)&smem[0][0][0][0];
#define CS(r_, n_) Cs[(r_) * 133 + (n_)]
    int v_blk = m_blk >> 2;
    for (int h = 0; h < 2; h++) {
        __syncthreads();
        if (wm == h) {
#pragma unroll
            for (int fi = 0; fi < 4; fi++)
#pragma unroll
                for (int fj = 0; fj < 4; fj++) {
                    int ml = fi * 16 + quad * 4;
                    int n  = wn * 64 + fj * 16 + l15;
#pragma unroll
                    for (int reg = 0; reg < 4; reg++)
                        CS(ml + reg, n) = acc[fi][fj][reg];
                }
        }
        __syncthreads();
#pragma unroll
        for (int i = 0; i < 8; i++) {
            int idx = tid + i * 256;          // 0..2047
            int v4  = idx & 3;                // float4-chunk of v
            int o   = (idx >> 2) & 127;
            int b   = idx >> 9;               // 0..3
            int vl  = v4 * 4;
            float bv = bias[o];
            float r0 = CS((vl + 0) * 4 + b, o) + bv;
            float r1 = CS((vl + 1) * 4 + b, o) + bv;
            float r2 = CS((vl + 2) * 4 + b, o) + bv;
            float r3 = CS((vl + 3) * 4 + b, o) + bv;
            int v0 = v_blk + h * 16 + vl;
            float* op = out + ((size_t)b * C_OUT + o) * V_N + v0;
            if (v0 + 3 < V_N) {
                *(float4*)op = make_float4(r0, r1, r2, r3);
            } else {
                if (v0     < V_N) op[0] = r0;
                if (v0 + 1 < V_N) op[1] = r1;
                if (v0 + 2 < V_N) op[2] = r2;
                if (v0 + 3 < V_N) op[3] = r3;
            }
        }
    }
#undef CS
}

// ---------------------------------------------------------------------------
extern "C" void kernel_launch(void* const* d_in, const int* in_sizes, int n_in,
                              void* d_out, int out_size, void* d_ws, size_t ws_size,
                              hipStream_t stream) {
    const float* x        = (const float*)d_in[0];
    const int*   edge_row = (const int*)  d_in[1];
    const int*   edge_col = (const int*)  d_in[2];
    const float* edge_val = (const float*)d_in[3];
    const float* weights  = (const float*)d_in[4];
    const float* biases   = (const float*)d_in[5];
    float* out = (float*)d_out;

    // workspace layout: x0..x3 (bf16, V*F each) | Wt (bf16) | int arrays | edges
    const size_t XSZ = (size_t)V_N * F_N;         // 25.6M elements
    ushort_t* x0 = (ushort_t*)d_ws;
    ushort_t* x1 = x0 + XSZ;
    ushort_t* x2 = x1 + XSZ;
    ushort_t* x3 = x2 + XSZ;
    ushort_t* Wt = x3 + XSZ;                      // 4*128*128
    int* iw      = (int*)(Wt + 4 * 128 * 128);
    int* row_ptr = iw;                            // V+1
    int* counts  = iw + 50016;
    int* nxt     = iw + 100032;
    int* blk_sums= iw + 150048;                   // 49 used (64 reserved)
    int2* edges  = (int2*)(iw + 150176);          // E packed {col, val}
    // total ws ~ 212 MB

    // 1) fused prep: transpose -> x0 | histogram -> counts | weights -> Wt
    hipMemsetAsync(counts, 0, V_N * sizeof(int), stream);
    k_prep<<<NPREP, 256, 0, stream>>>(x, x0, edge_row, counts, weights, Wt);

    // 2) CSR scan + scatter
    k_scan_blk<<<SCAN_NB, 256, 0, stream>>>(counts, row_ptr, blk_sums);
    k_scan_add<<<SCAN_NB, 256, 0, stream>>>(blk_sums, row_ptr, nxt);
    k_scatter<<<(E_N + 255) / 256, 256, 0, stream>>>(edge_row, edge_col, edge_val,
                                                     nxt, edges);

    // 3) Pure power chain z_k = A z_{k-1} (bf16 state, fp32 accumulate)
    k_spmm_bf16<<<V_N * 2 / 4, 256, 0, stream>>>(row_ptr, edges, x0, x1);
    k_spmm_bf16<<<V_N * 2 / 4, 256, 0, stream>>>(row_ptr, edges, x1, x2);
    k_spmm_bf16<<<V_N * 2 / 4, 256, 0, stream>>>(row_ptr, edges, x2, x3);

    // 4) fused MFMA GEMM (folded weights) + bias + transpose to (B,Cout,V)
    k_gemm_mfma<<<(M_TOT + 127) / 128, 256, 0, stream>>>(x0, x1, x2, x3, Wt,
                                                         biases, out);
}